// Round 11
// baseline (356.262 us; speedup 1.0000x reference)
//
#include <hip/hip_runtime.h>

#define DIN 128
#define BN_EPS 1e-5f

typedef __attribute__((ext_vector_type(8))) short bf16x8;
typedef __attribute__((ext_vector_type(8))) unsigned short us8;
typedef __attribute__((ext_vector_type(4))) float f32x4;

__device__ __forceinline__ ushort f2bf(float f) {
    unsigned u = __float_as_uint(f);
    u += 0x7fffu + ((u >> 16) & 1u);
    return (ushort)(u >> 16);
}
__device__ __forceinline__ float bf2f(ushort h) {
    return __uint_as_float(((unsigned)h) << 16);
}

// light barrier: LDS-visibility only (lgkmcnt(0)); vmcnt stays counted (R10: neutral vs
// __syncthreads, kept since it never hurts and preserves in-flight prefetch).
__device__ __forceinline__ void lds_barrier() {
    asm volatile("s_waitcnt lgkmcnt(0)" ::: "memory");
    __builtin_amdgcn_s_barrier();
    __builtin_amdgcn_sched_barrier(0);
}

// ======== LDS-shared streaming GEMM v5 ========
// R8/R10 base (block-shared A strip, double-buffered LDS, depth-2 prefetch,
// BN-in-staging, BNIN=2 dual-source, 512-block grids, 1 barrier/strip) +
// NEW: LDS-transpose epilogue. Old epilogue: 16x 2B scalar stores/lane -> each 128B
// C-line assembled from partial writes of different waves -> L2 partial-line RMW
// (FETCH ~ WRITE/2 observed) + store backpressure. New: pack acc (bit-identical f2bf)
// into padded cbuf, barrier (the existing one), then 256 threads store us8 chunks ->
// full 128B lines, 2-4 coalesced store insts/strip instead of 64.
template<int KC, int NT, int LOGNG, int STATS, int BNIN>
__global__ __launch_bounds__(256) void gemm_lds(
    const ushort* __restrict__ A, const ushort* __restrict__ BT,
    ushort* __restrict__ C, int mStrips, int N,
    float* __restrict__ gsums, float* __restrict__ gsqs,
    const float* __restrict__ isums, const float* __restrict__ isqs,
    const float* __restrict__ igam, const float* __restrict__ ibet,
    float invM, float negSlope,
    const ushort* __restrict__ A2)
{
    constexpr int K = KC * 32;           // K in shorts
    constexpr int CPR = KC * 4;          // 16B chunks per row
    constexpr int LOGCPR = (KC == 4) ? 4 : 5;
    constexpr int LPL = KC / 4;          // staging chunks per lane (1 or 2)
    constexpr int NCOL = 64 * NT;        // block's output cols (4 waves x 16*NT)
    constexpr int LOGNCOL = (NT == 4) ? 8 : 7;
    constexpr int PC = NCOL + 8;         // padded cbuf row stride (shorts)
    __shared__ ushort abuf[2][16 * K];   // double-buffered A strip
    __shared__ ushort cbuf[2][16 * PC];  // double-buffered C strip (padded)

    int tid = threadIdx.x;
    int lane = tid & 63;
    int w = tid >> 6;
    int cl = lane & 15, q = lane >> 4;
    int grp = blockIdx.x & ((1 << LOGNG) - 1);
    int s0 = blockIdx.x >> LOGNG;
    int TT = gridDim.x >> LOGNG;         // strip stride
    int colStart = grp * NCOL;           // block's first output col
    int colBase = colStart + w * (16 * NT);
    int colLoc = w * (16 * NT);          // within-block col base
    int chBase = w * (16 * KC);          // this wave's staging chunk range

    // B fragments: loaded once (weights L2-resident)
    bf16x8 bf[NT][KC];
    #pragma unroll
    for (int nt = 0; nt < NT; nt++) {
        const ushort* bp = BT + (long)(colBase + nt * 16 + cl) * K + q * 8;
        #pragma unroll
        for (int kc = 0; kc < KC; kc++)
            bf[nt][kc] = *(const bf16x8*)(bp + kc * 32);
    }

    // BN-in-staging params: the lane's staging chunks share one K-column
    float sc8[8], sh8[8];
    const ushort* dsrc = A;              // BNIN==2: per-lane source base
    int dcol = 0;
    if (BNIN == 1) {
        int cb = ((chBase + lane) & (CPR - 1)) * 8;
        #pragma unroll
        for (int e = 0; e < 8; e++) {
            float mean = isums[cb + e] * invM;
            float var = isqs[cb + e] * invM - mean * mean;
            float s = igam[cb + e] * rsqrtf(var + BN_EPS);
            sc8[e] = s;
            sh8[e] = ibet[cb + e] - mean * s;
        }
    } else if (BNIN == 2) {
        int c = (chBase + lane) & (CPR - 1);
        dsrc = (c < 16) ? A : A2;
        dcol = (c & 15) * 8;
        if (c < 16) {
            int cb = c * 8;
            #pragma unroll
            for (int e = 0; e < 8; e++) {
                float mean = isums[cb + e] * invM;
                float var = isqs[cb + e] * invM - mean * mean;
                float s = igam[cb + e] * rsqrtf(var + BN_EPS);
                sc8[e] = s;
                sh8[e] = ibet[cb + e] - mean * s;
            }
        } else {
            #pragma unroll
            for (int e = 0; e < 8; e++) { sc8[e] = 1.0f; sh8[e] = 0.0f; }
        }
    }

    float ssum[NT], ssq[NT];
    #pragma unroll
    for (int nt = 0; nt < NT; nt++) { ssum[nt] = 0.f; ssq[nt] = 0.f; }

    auto stage_load = [&](us8 (&stg)[LPL], int strip) {
        if (BNIN == 2) {
            #pragma unroll
            for (int u = 0; u < LPL; u++) {
                int r = (chBase + u * 64 + lane) >> LOGCPR;
                stg[u] = *(const us8*)(dsrc + ((long)(strip * 16 + r)) * 128 + dcol);
            }
        } else {
            const ushort* As = A + (long)strip * 16 * K;
            #pragma unroll
            for (int u = 0; u < LPL; u++)
                stg[u] = *(const us8*)(As + (chBase + u * 64 + lane) * 8);
        }
    };
    auto stage_write = [&](int buf, us8 (&stg)[LPL]) {
        #pragma unroll
        for (int u = 0; u < LPL; u++) {
            int ch = chBase + u * 64 + lane;
            int r = ch >> LOGCPR;
            int c = ch & (CPR - 1);
            us8 v = stg[u];
            if (BNIN != 0) {
                us8 o;
                #pragma unroll
                for (int e = 0; e < 8; e++) {
                    float f = bf2f(v[e]) * sc8[e] + sh8[e];
                    f = (f > 0.f) ? f : f * negSlope;
                    o[e] = f2bf(f);
                }
                v = o;
            }
            *(us8*)(abuf[buf] + (((r << LOGCPR) + (c ^ (r & 7))) * 8)) = v;
        }
    };

    us8 stgA[LPL], stgB[LPL];
    int s = s0;
    // prologue: abuf[0] <- s0; stgB <- s0+TT; stgA <- s0+2TT (in flight)
    stage_load(stgA, s);
    if (s + TT < mStrips) stage_load(stgB, s + TT);
    stage_write(0, stgA);
    if (s + 2 * TT < mStrips) stage_load(stgA, s + 2 * TT);
    lds_barrier();
    int cur = 0;

#define GEMM_STEP(STG)                                                                  \
    {                                                                                   \
        bf16x8 af[KC];                                                                  \
        _Pragma("unroll")                                                               \
        for (int kc = 0; kc < KC; kc++)                                                 \
            af[kc] = *(const bf16x8*)(abuf[cur] +                                       \
                     (((cl << LOGCPR) + ((kc * 4 + q) ^ (cl & 7))) * 8));               \
        if (s + TT < mStrips) stage_write(cur ^ 1, STG);                                \
        if (s + 3 * TT < mStrips) stage_load(STG, s + 3 * TT);                          \
        f32x4 acc[NT] = {};                                                             \
        _Pragma("unroll")                                                               \
        for (int kc = 0; kc < KC; kc++)                                                 \
            _Pragma("unroll")                                                           \
            for (int nt = 0; nt < NT; nt++)                                             \
                acc[nt] = __builtin_amdgcn_mfma_f32_16x16x32_bf16(af[kc], bf[nt][kc],   \
                                                                  acc[nt], 0, 0, 0);    \
        _Pragma("unroll")                                                               \
        for (int nt = 0; nt < NT; nt++) {                                               \
            _Pragma("unroll")                                                           \
            for (int r = 0; r < 4; r++) {                                               \
                float v = acc[nt][r];                                                   \
                cbuf[cur][(q * 4 + r) * PC + colLoc + nt * 16 + cl] = f2bf(v);          \
                if (STATS) { ssum[nt] += v; ssq[nt] += v * v; }                         \
            }                                                                           \
        }                                                                               \
        lds_barrier();                                                                  \
        {                                                                               \
            int rowBase = s * 16;                                                       \
            _Pragma("unroll")                                                           \
            for (int it = 0; it < NT / 2; it++) {                                       \
                int lid = (it * 256 + tid) * 8;                                         \
                int rr = lid >> LOGNCOL;                                                \
                int cc = lid & (NCOL - 1);                                              \
                us8 vv = *(const us8*)(cbuf[cur] + rr * PC + cc);                       \
                *(us8*)&C[(long)(rowBase + rr) * N + colStart + cc] = vv;               \
            }                                                                           \
        }                                                                               \
        s += TT; cur ^= 1;                                                              \
    }

    while (true) {
        GEMM_STEP(stgB);
        if (s >= mStrips) break;
        GEMM_STEP(stgA);
        if (s >= mStrips) break;
    }
#undef GEMM_STEP

    if (STATS) {
        #pragma unroll
        for (int nt = 0; nt < NT; nt++) {
            ssum[nt] += __shfl_xor(ssum[nt], 16, 64);
            ssum[nt] += __shfl_xor(ssum[nt], 32, 64);
            ssq[nt]  += __shfl_xor(ssq[nt], 16, 64);
            ssq[nt]  += __shfl_xor(ssq[nt], 32, 64);
        }
        if (q == 0) {
            #pragma unroll
            for (int nt = 0; nt < NT; nt++) {
                atomicAdd(&gsums[colBase + nt * 16 + cl], ssum[nt]);
                atomicAdd(&gsqs[colBase + nt * 16 + cl], ssq[nt]);
            }
        }
    }
}

// ======== fused setup: convert nodes -> bf16, transpose weights, zero stats + degi/cursor ========
__global__ __launch_bounds__(256) void setup_all(
    const float* __restrict__ nodes, ushort* __restrict__ Xbf, int nConv4, int nbConv,
    const float* __restrict__ W0, const float* __restrict__ W1,
    const float* __restrict__ W2, const float* __restrict__ W3,
    const float* __restrict__ W4, const float* __restrict__ W5,
    ushort* __restrict__ WT,
    int* __restrict__ zeroInts, int nZero4, int nbZero,
    float* __restrict__ stats)
{
    int b = blockIdx.x;
    int tid = threadIdx.x;
    if (b < nbConv) {
        int t = b * 256 + tid;
        if (t < nConv4) {
            float4 v = *(const float4*)&nodes[(long)t * 4];
            ushort4 o; o.x = f2bf(v.x); o.y = f2bf(v.y); o.z = f2bf(v.z); o.w = f2bf(v.w);
            *(ushort4*)&Xbf[(long)t * 4] = o;
        }
        return;
    }
    b -= nbConv;
    if (b < 768) {
        int seg = b >> 7;
        const float* W; int logK, dstBase, stride, kOff;
        switch (seg) {
            case 0: W = W0; logK = 7; dstBase = 0;      stride = 128; kOff = 0;   break;
            case 1: W = W1; logK = 8; dstBase = 32768;  stride = 256; kOff = 0;   break;
            case 2: W = W2; logK = 7; dstBase = 65536;  stride = 256; kOff = 0;   break;
            case 3: W = W3; logK = 7; dstBase = 65536;  stride = 256; kOff = 128; break;
            case 4: W = W4; logK = 8; dstBase = 131072; stride = 256; kOff = 0;   break;
            default:W = W5; logK = 8; dstBase = 163840; stride = 256; kOff = 0;   break;
        }
        int t = (b & 127) * 256 + tid;
        int N = 32768 >> logK;
        int k = t & ((1 << logK) - 1);
        int n = t >> logK;
        WT[(long)dstBase + (long)n * stride + kOff + k] = f2bf(W[(long)k * N + n]);
        return;
    }
    b -= 768;
    if (b < nbZero) {
        int t = b * 256 + tid;
        if (t < nZero4) *(int4*)&zeroInts[(long)t * 4] = make_int4(0, 0, 0, 0);
        return;
    }
    b -= nbZero;
    int t = b * 256 + tid;
    if (t < 512) *(float4*)&stats[(long)t * 4] = make_float4(0, 0, 0, 0);
}

// ======== BN params folded, fp32 in-place (final output, 128 ch) ========
__global__ __launch_bounds__(256) void bnact_f32(
    float* __restrict__ X,
    const float* __restrict__ sums, const float* __restrict__ sqs,
    const float* __restrict__ gamma, const float* __restrict__ beta, float invM,
    int nRows, float negSlope)
{
    __shared__ float ssc[128], ssh[128];
    int tid = threadIdx.x;
    if (tid < 128) {
        float mean = sums[tid] * invM;
        float var = sqs[tid] * invM - mean * mean;
        float sc = gamma[tid] * rsqrtf(var + BN_EPS);
        ssc[tid] = sc;
        ssh[tid] = beta[tid] - mean * sc;
    }
    __syncthreads();
    int cb = (tid * 4) & 127;
    float4 sc = *(const float4*)&ssc[cb];
    float4 sh = *(const float4*)&ssh[cb];
    int r0 = blockIdx.x * 8 + ((tid * 4) >> 7);
    int rstride = gridDim.x * 8;
    for (int row = r0; row < nRows; row += rstride) {
        float4 v = *(const float4*)&X[(long)row * 128 + cb];
        float a = v.x * sc.x + sh.x; a = (a > 0.f) ? a : a * negSlope;
        float b = v.y * sc.y + sh.y; b = (b > 0.f) ? b : b * negSlope;
        float d = v.z * sc.z + sh.z; d = (d > 0.f) ? d : d * negSlope;
        float e = v.w * sc.w + sh.w; e = (e > 0.f) ? e : e * negSlope;
        *(float4*)&X[(long)row * 128 + cb] = make_float4(a, b, d, e);
    }
}

// ======== column stats for final output (128 cols, register accum) ========
__global__ __launch_bounds__(256) void colstats128(
    const float* __restrict__ X, float* __restrict__ sums, float* __restrict__ sqs, int M)
{
    __shared__ float ss[128], sq[128];
    int tid = threadIdx.x;
    if (tid < 128) { ss[tid] = 0.f; sq[tid] = 0.f; }
    __syncthreads();
    int cg = tid & 31;
    int worker = (blockIdx.x << 3) | (tid >> 5);
    int totalW = gridDim.x << 3;
    float4 s4 = make_float4(0, 0, 0, 0), q4 = make_float4(0, 0, 0, 0);
    for (int r = worker; r < M; r += totalW) {
        float4 v = *(const float4*)&X[(long)r * 128 + cg * 4];
        s4.x += v.x; s4.y += v.y; s4.z += v.z; s4.w += v.w;
        q4.x += v.x * v.x; q4.y += v.y * v.y; q4.z += v.z * v.z; q4.w += v.w * v.w;
    }
    atomicAdd(&ss[cg * 4 + 0], s4.x); atomicAdd(&sq[cg * 4 + 0], q4.x);
    atomicAdd(&ss[cg * 4 + 1], s4.y); atomicAdd(&sq[cg * 4 + 1], q4.y);
    atomicAdd(&ss[cg * 4 + 2], s4.z); atomicAdd(&sq[cg * 4 + 2], q4.z);
    atomicAdd(&ss[cg * 4 + 3], s4.w); atomicAdd(&sq[cg * 4 + 3], q4.w);
    __syncthreads();
    if (tid < 128) { atomicAdd(&sums[tid], ss[tid]); atomicAdd(&sqs[tid], sq[tid]); }
}

// ======== CSR build ========
__global__ void degcount_kernel(const int* __restrict__ dst, int* __restrict__ degi, int E)
{
    int i = blockIdx.x * blockDim.x + threadIdx.x;
    if (i < E) atomicAdd(&degi[dst[i]], 1);
}

__global__ __launch_bounds__(256) void scan_block_sums(const int* __restrict__ degi,
                                                       int* __restrict__ partial, int n)
{
    __shared__ int s[256];
    int i = blockIdx.x * 256 + threadIdx.x;
    s[threadIdx.x] = (i < n) ? degi[i] : 0;
    __syncthreads();
    for (int off = 128; off > 0; off >>= 1) {
        if (threadIdx.x < off) s[threadIdx.x] += s[threadIdx.x + off];
        __syncthreads();
    }
    if (threadIdx.x == 0) partial[blockIdx.x] = s[0];
}

// scan_final also reduces the block-offset from raw per-block sums (scan_partials folded in)
__global__ __launch_bounds__(256) void scan_final(const int* __restrict__ degi,
                                                  const int* __restrict__ partial,
                                                  int* __restrict__ rowstart, int n, int nb)
{
    __shared__ int s[256];
    __shared__ int ps[256];
    int tid = threadIdx.x;
    ps[tid] = (tid < nb && tid < (int)blockIdx.x) ? partial[tid] : 0;
    __syncthreads();
    for (int off = 128; off > 0; off >>= 1) {
        if (tid < off) ps[tid] += ps[tid + off];
        __syncthreads();
    }
    int offset = ps[0];
    int i = blockIdx.x * 256 + tid;
    int v = (i < n) ? degi[i] : 0;
    s[tid] = v;
    __syncthreads();
    for (int off = 1; off < 256; off <<= 1) {
        int t = (tid >= off) ? s[tid - off] : 0;
        __syncthreads();
        s[tid] += t;
        __syncthreads();
    }
    if (i < n) rowstart[i] = offset + s[tid] - v;
}

__global__ void fillcsr_kernel(const int* __restrict__ src, const int* __restrict__ dst,
                               const int* __restrict__ rowstart, int* __restrict__ cursor,
                               int* __restrict__ csr, int E)
{
    int i = blockIdx.x * blockDim.x + threadIdx.x;
    if (i < E) {
        int d = dst[i];
        int p = atomicAdd(&cursor[d], 1);
        csr[rowstart[d] + p] = src[i];
    }
}

// ======== gather16_bn: 16-lane group per edge, BN_L1+ReLU applied inline on raw input ========
__global__ __launch_bounds__(256) void gather16_bn(
    const ushort* __restrict__ X, const int* __restrict__ rowstart,
    const int* __restrict__ degi, const int* __restrict__ csr,
    ushort* __restrict__ AGG, int nN,
    const float* __restrict__ isums, const float* __restrict__ isqs,
    const float* __restrict__ igam, const float* __restrict__ ibet, float invM)
{
    int wv = (blockIdx.x * blockDim.x + threadIdx.x) >> 6;
    int lane = threadIdx.x & 63;
    if (wv >= nN) return;
    int g = lane >> 4;        // edge slot 0..3
    int sc = lane & 15;       // 16-B chunk of row
    float sc8[8], sh8[8];
    {
        int cb = sc * 8;
        #pragma unroll
        for (int e = 0; e < 8; e++) {
            float mean = isums[cb + e] * invM;
            float var = isqs[cb + e] * invM - mean * mean;
            float s = igam[cb + e] * rsqrtf(var + BN_EPS);
            sc8[e] = s;
            sh8[e] = ibet[cb + e] - mean * s;
        }
    }
    int start = rowstart[wv], d = degi[wv];
    const ushort* Xc = X + sc * 8;
    float acc[8] = {};
    auto accbn8 = [&](us8 v) {
        #pragma unroll
        for (int e = 0; e < 8; e++)
            acc[e] += fmaxf(bf2f(v[e]) * sc8[e] + sh8[e], 0.f);
    };
    if (d > 0) {
        int dm = (d < 64) ? d : 64;
        int idx_l = csr[start + ((lane < dm) ? lane : (dm - 1))];
        int j = 0;
        for (; j + 8 <= dm; j += 8) {
            int i0 = __shfl(idx_l, j + g, 64);
            int i1 = __shfl(idx_l, j + 4 + g, 64);
            us8 v0 = *(const us8*)(Xc + (long)i0 * 128);
            us8 v1 = *(const us8*)(Xc + (long)i1 * 128);
            accbn8(v0);
            accbn8(v1);
        }
        if (j + 4 <= dm) {
            int i0 = __shfl(idx_l, j + g, 64);
            us8 v0 = *(const us8*)(Xc + (long)i0 * 128);
            accbn8(v0);
            j += 4;
        }
        int rem = dm - j;
        if (rem > 0) {
            int sl = j + ((g < rem) ? g : (rem - 1));
            int i0 = __shfl(idx_l, sl, 64);
            if (g < rem) {
                us8 v0 = *(const us8*)(Xc + (long)i0 * 128);
                accbn8(v0);
            }
        }
        for (int jj = 64; jj < d; jj += 4) {     // rare: degree > 64
            if (jj + g < d) {
                int i0 = csr[start + jj + g];
                us8 v0 = *(const us8*)(Xc + (long)i0 * 128);
                accbn8(v0);
            }
        }
    }
    #pragma unroll
    for (int e = 0; e < 8; e++) {
        acc[e] += __shfl_xor(acc[e], 16, 64);
        acc[e] += __shfl_xor(acc[e], 32, 64);
    }
    if (g == 0) {
        float inv = 1.f / fmaxf((float)d, 1.f);
        us8 o;
        #pragma unroll
        for (int e = 0; e < 8; e++) o[e] = f2bf(acc[e] * inv);
        *(us8*)(AGG + (long)wv * 128 + sc * 8) = o;
    }
}

// fused gather2: out = mean(Z[src, 0:128]) + Z[dst, 128:256]  (fp32 out, 128 cols)
__device__ __forceinline__ void acc8(float acc[8], us8 v) {
    #pragma unroll
    for (int e = 0; e < 8; e++) acc[e] += bf2f(v[e]);
}

__global__ __launch_bounds__(256) void gather16_fuse(
    const ushort* __restrict__ Z, const int* __restrict__ rowstart,
    const int* __restrict__ degi, const int* __restrict__ csr,
    float* __restrict__ O, int nN)
{
    int wv = (blockIdx.x * blockDim.x + threadIdx.x) >> 6;
    int lane = threadIdx.x & 63;
    if (wv >= nN) return;
    int g = lane >> 4;
    int sc = lane & 15;
    int start = rowstart[wv], d = degi[wv];
    const ushort* Zc = Z + sc * 8;
    us8 selfv = *(const us8*)(Zc + (long)wv * 256 + 128);   // independent, issued early
    float acc[8] = {};
    if (d > 0) {
        int dm = (d < 64) ? d : 64;
        int idx_l = csr[start + ((lane < dm) ? lane : (dm - 1))];
        int j = 0;
        for (; j + 8 <= dm; j += 8) {
            int i0 = __shfl(idx_l, j + g, 64);
            int i1 = __shfl(idx_l, j + 4 + g, 64);
            us8 v0 = *(const us8*)(Zc + (long)i0 * 256);
            us8 v1 = *(const us8*)(Zc + (long)i1 * 256);
            acc8(acc, v0);
            acc8(acc, v1);
        }
        if (j + 4 <= dm) {
            int i0 = __shfl(idx_l, j + g, 64);
            us8 v0 = *(const us8*)(Zc + (long)i0 * 256);
            acc8(acc, v0);
            j += 4;
        }
        int rem = dm - j;
        if (rem > 0) {
            int sl = j + ((g < rem) ? g : (rem - 1));
            int i0 = __shfl(idx_l, sl, 64);
            if (g < rem) {
                us8 v0 = *(const us8*)(Zc + (long)i0 * 256);
                acc8(acc, v0);
            }
        }
        for (int jj = 64; jj < d; jj += 4) {
            if (jj + g < d) {
                int i0 = csr[start + jj + g];
                us8 v0 = *(const us8*)(Zc + (long)i0 * 256);
                acc8(acc, v0);
            }
        }
    }
    #pragma unroll
    for (int e = 0; e < 8; e++) {
        acc[e] += __shfl_xor(acc[e], 16, 64);
        acc[e] += __shfl_xor(acc[e], 32, 64);
    }
    if (g == 0) {
        float inv = 1.f / fmaxf((float)d, 1.f);
        float r[8];
        #pragma unroll
        for (int e = 0; e < 8; e++) r[e] = acc[e] * inv + bf2f(selfv[e]);
        float* op = O + (long)wv * 128 + sc * 8;
        *(float4*)op = make_float4(r[0], r[1], r[2], r[3]);
        *(float4*)(op + 4) = make_float4(r[4], r[5], r[6], r[7]);
    }
}

extern "C" void kernel_launch(void* const* d_in, const int* in_sizes, int n_in,
                              void* d_out, int out_size, void* d_ws, size_t ws_size,
                              hipStream_t stream)
{
    const float* nodes = (const float*)d_in[0];
    const int*   src   = (const int*)d_in[1];
    const int*   dst   = (const int*)d_in[2];
    const float* Wf1   = (const float*)d_in[3];
    const float* gf1   = (const float*)d_in[5];
    const float* bef1  = (const float*)d_in[6];
    const float* Wf2   = (const float*)d_in[7];
    const float* gf2   = (const float*)d_in[9];
    const float* bef2  = (const float*)d_in[10];
    const float* Ws1   = (const float*)d_in[11];
    const float* Wn1   = (const float*)d_in[12];
    const float* gs1   = (const float*)d_in[14];
    const float* bs1   = (const float*)d_in[15];
    const float* Ws2   = (const float*)d_in[16];
    const float* Wn2   = (const float*)d_in[17];
    const float* gs2   = (const float*)d_in[19];
    const float* bs2   = (const float*)d_in[20];
    // pre-BN biases (bf1,bf2,b1,b2) cancel under BatchNorm -> skipped

    int nN = in_sizes[0] / DIN;   // 50000
    int nE = in_sizes[1];         // 600000
    float* out = (float*)d_out;
    int mStrips = nN / 16;        // 3125 (exact)
    float invM = 1.0f / nN;

    // ---- workspace (identical layout to passing version) ----
    ushort* PRE = (ushort*)d_ws;                      // nN*256 bf16 raw GEMM out
    ushort* BF1 = PRE + (size_t)nN * 256;             // nN*256 bf16 (Xn / FF2 raw, compact 128)
    ushort* BF2 = BF1 + (size_t)nN * 256;             // nN*256 bf16 (AGG compact / Z)
    float* stats = (float*)(BF2 + (size_t)nN * 256);  // 2048 floats, 4 layer-regions
    float* scale = stats + 2048;                      // 256 (unused, kept for layout)
    float* shift = scale + 256;                       // 256 (unused, kept for layout)
    ushort* WT   = (ushort*)(shift + 256);            // 196608 shorts
    int* degi     = (int*)(WT + 196608);              // nN
    int* cursor   = degi + nN;                        // nN (adjacent: zeroed together)
    int* rowstart = cursor + nN;                      // nN
    int* partial  = rowstart + nN;                    // 256
    int* csr      = partial + 256;                    // nE

    ushort* Wf1T = WT;
    ushort* Wf2T = WT + 32768;
    ushort* Wc1T = WT + 65536;
    ushort* Wc2T = WT + 131072;
    ushort* AGG  = BF2;                               // compact nN*128 agg buffer

    dim3 blk(256);
    auto cdiv = [](int a, int b) { return (a + b - 1) / b; };
    int nScanBlocks = cdiv(nN, 256);                  // 196 (must be <= 256)

    // ---- fused setup: convert + weight transpose + zero stats/degi/cursor ----
    int nConv4 = nN * DIN / 4;
    int nbConv = cdiv(nConv4, 256);
    int nZero4 = (2 * nN) / 4;
    int nbZero = cdiv(nZero4, 256);
    setup_all<<<dim3(nbConv + 768 + nbZero + 2), blk, 0, stream>>>(
        nodes, BF1, nConv4, nbConv,
        Wf1, Wf2, Ws1, Wn1, Wn2, Ws2, WT,
        degi, nZero4, nbZero, stats);

    // ---- CSR build ----
    degcount_kernel<<<dim3(cdiv(nE, 256)), blk, 0, stream>>>(dst, degi, nE);
    scan_block_sums<<<dim3(nScanBlocks), blk, 0, stream>>>(degi, partial, nN);
    scan_final<<<dim3(nScanBlocks), blk, 0, stream>>>(degi, partial, rowstart, nN, nScanBlocks);
    fillcsr_kernel<<<dim3(cdiv(nE, 256)), blk, 0, stream>>>(src, dst, rowstart, cursor, csr, nE);

    // ---- FF1: PRE = Xn @ Wf1T (K=128, N=256, stats->L0), plain staging ----
    gemm_lds<4, 4, 0, 1, 0><<<dim3(512), blk, 0, stream>>>(
        BF1, Wf1T, PRE, mStrips, 256, stats, stats + 256,
        nullptr, nullptr, nullptr, nullptr, 0.f, 0.f, nullptr);

    // ---- FF2: BF1 = act(BN_L0(PRE)) @ Wf2T (BNIN=1; K=256, N=128 compact, stats->L1) ----
    gemm_lds<8, 2, 0, 1, 1><<<dim3(512), blk, 0, stream>>>(
        PRE, Wf2T, BF1, mStrips, 128, stats + 512, stats + 768,
        stats, stats + 256, gf1, bef1, invM, 0.0f, nullptr);

    // ---- gather1 (BN fused): AGG = mean-gather(ReLU(BN_L1(BF1))) ----
    gather16_bn<<<dim3(cdiv(nN * 64, 256)), blk, 0, stream>>>(
        BF1, rowstart, degi, csr, AGG, nN,
        stats + 512, stats + 768, gf2, bef2, invM);

    // ---- SAGE1: PRE = [ReLU(BN_L1(BF1)) | AGG] @ [Ws1;Wn1] (BNIN=2 dual-source;
    //      K=256, N=256, stats->L2) ----
    gemm_lds<8, 4, 0, 1, 2><<<dim3(512), blk, 0, stream>>>(
        BF1, Wc1T, PRE, mStrips, 256, stats + 1024, stats + 1280,
        stats + 512, stats + 768, gf2, bef2, invM, 0.0f, AGG);

    // ---- SAGE2: BF2 = act(BN_L2(PRE)) @ [Wn2|Ws2] (BNIN=1; K=256, N=256, NT=2, no stats) ----
    gemm_lds<8, 2, 1, 0, 1><<<dim3(512), blk, 0, stream>>>(
        PRE, Wc2T, BF2, mStrips, 256, nullptr, nullptr,
        stats + 1024, stats + 1280, gs1, bs1, invM, 0.01f, nullptr);

    // ---- gather_fuse -> out(fp32) ----
    gather16_fuse<<<dim3(cdiv(nN * 64, 256)), blk, 0, stream>>>(BF2, rowstart, degi, csr, out, nN);

    // ---- final: colstats -> fused BN+LReLU on out ----
    colstats128<<<dim3(120), blk, 0, stream>>>(out, stats + 1536, stats + 1792, nN);
    bnact_f32<<<dim3(2048), blk, 0, stream>>>(out, stats + 1536, stats + 1792, gs2, bs2, invM,
                                              nN, 0.01f);
}

// Round 12
// 344.402 us; speedup vs baseline: 1.0344x; 1.0344x over previous
//
#include <hip/hip_runtime.h>

#define DIN 128
#define BN_EPS 1e-5f

typedef __attribute__((ext_vector_type(8))) short bf16x8;
typedef __attribute__((ext_vector_type(8))) unsigned short us8;
typedef __attribute__((ext_vector_type(4))) float f32x4;

__device__ __forceinline__ ushort f2bf(float f) {
    unsigned u = __float_as_uint(f);
    u += 0x7fffu + ((u >> 16) & 1u);
    return (ushort)(u >> 16);
}
__device__ __forceinline__ float bf2f(ushort h) {
    return __uint_as_float(((unsigned)h) << 16);
}
__device__ __forceinline__ f32x4 asf4(us8 v) {
    union { us8 u; f32x4 f; } x; x.u = v; return x.f;
}

// ======== LDS-shared streaming GEMM (R8-best config) ========
// Block-shared A strip, double-buffered LDS, depth-2 prefetch, 1 barrier/strip
// (__syncthreads - the R8 351us config), 512-block grids.
// Staging transform modes:
//   BNIN=0: plain bf16 copy
//   BNIN=1: BN+act of previous layer applied during staging (reads raw PRE)
//   BNIN=2: dual-source [h|agg] with BN+ReLU on h-half, identity on agg-half
//   BNIN=3: CVT - stage directly from fp32 source, f2bf convert in staging
//           (deletes the separate convert pass + its 25.6MB round trip; bit-identical)
template<int KC, int NT, int LOGNG, int STATS, int BNIN>
__global__ __launch_bounds__(256) void gemm_lds(
    const ushort* __restrict__ A, const ushort* __restrict__ BT,
    ushort* __restrict__ C, int mStrips, int N,
    float* __restrict__ gsums, float* __restrict__ gsqs,
    const float* __restrict__ isums, const float* __restrict__ isqs,
    const float* __restrict__ igam, const float* __restrict__ ibet,
    float invM, float negSlope,
    const ushort* __restrict__ A2)
{
    constexpr int K = KC * 32;           // K in shorts
    constexpr int CPR = KC * 4;          // 16B chunks per row
    constexpr int LOGCPR = (KC == 4) ? 4 : 5;
    constexpr int LPL = KC / 4;          // staging chunks per lane (1 or 2)
    constexpr int LPL2 = (BNIN == 3) ? 2 * LPL : LPL;   // regs (CVT: 2 us8 per chunk)
    __shared__ ushort abuf[2][16 * K];   // double-buffered strip (2x 4/8 KB)

    int tid = threadIdx.x;
    int lane = tid & 63;
    int w = tid >> 6;
    int cl = lane & 15, q = lane >> 4;
    int grp = blockIdx.x & ((1 << LOGNG) - 1);
    int s0 = blockIdx.x >> LOGNG;
    int TT = gridDim.x >> LOGNG;         // strip stride
    int colBase = grp * (4 * 16 * NT) + w * (16 * NT);
    int chBase = w * (16 * KC);          // this wave's staging chunk range

    // B fragments: loaded once (weights L2-resident)
    bf16x8 bf[NT][KC];
    #pragma unroll
    for (int nt = 0; nt < NT; nt++) {
        const ushort* bp = BT + (long)(colBase + nt * 16 + cl) * K + q * 8;
        #pragma unroll
        for (int kc = 0; kc < KC; kc++)
            bf[nt][kc] = *(const bf16x8*)(bp + kc * 32);
    }

    // BN-in-staging params: the lane's staging chunks share one K-column
    float sc8[8], sh8[8];
    const ushort* dsrc = A;              // BNIN==2: per-lane source base
    int dcol = 0;
    if (BNIN == 1) {
        int cb = ((chBase + lane) & (CPR - 1)) * 8;
        #pragma unroll
        for (int e = 0; e < 8; e++) {
            float mean = isums[cb + e] * invM;
            float var = isqs[cb + e] * invM - mean * mean;
            float s = igam[cb + e] * rsqrtf(var + BN_EPS);
            sc8[e] = s;
            sh8[e] = ibet[cb + e] - mean * s;
        }
    } else if (BNIN == 2) {
        int c = (chBase + lane) & (CPR - 1);
        dsrc = (c < 16) ? A : A2;
        dcol = (c & 15) * 8;
        if (c < 16) {
            int cb = c * 8;
            #pragma unroll
            for (int e = 0; e < 8; e++) {
                float mean = isums[cb + e] * invM;
                float var = isqs[cb + e] * invM - mean * mean;
                float s = igam[cb + e] * rsqrtf(var + BN_EPS);
                sc8[e] = s;
                sh8[e] = ibet[cb + e] - mean * s;
            }
        } else {
            #pragma unroll
            for (int e = 0; e < 8; e++) { sc8[e] = 1.0f; sh8[e] = 0.0f; }
        }
    }

    float ssum[NT], ssq[NT];
    #pragma unroll
    for (int nt = 0; nt < NT; nt++) { ssum[nt] = 0.f; ssq[nt] = 0.f; }

    auto stage_load = [&](us8 (&stg)[LPL2], int strip) {
        if (BNIN == 3) {
            const float* Af = (const float*)A;
            #pragma unroll
            for (int u = 0; u < LPL; u++) {
                int ch = chBase + u * 64 + lane;
                int r = ch >> LOGCPR;
                int c = ch & (CPR - 1);
                const float* p = Af + (long)(strip * 16 + r) * K + c * 8;
                stg[2 * u]     = *(const us8*)p;
                stg[2 * u + 1] = *(const us8*)(p + 4);
            }
        } else if (BNIN == 2) {
            #pragma unroll
            for (int u = 0; u < LPL; u++) {
                int r = (chBase + u * 64 + lane) >> LOGCPR;
                stg[u] = *(const us8*)(dsrc + ((long)(strip * 16 + r)) * 128 + dcol);
            }
        } else {
            const ushort* As = A + (long)strip * 16 * K;
            #pragma unroll
            for (int u = 0; u < LPL; u++)
                stg[u] = *(const us8*)(As + (chBase + u * 64 + lane) * 8);
        }
    };
    auto stage_write = [&](int buf, us8 (&stg)[LPL2]) {
        #pragma unroll
        for (int u = 0; u < LPL; u++) {
            int ch = chBase + u * 64 + lane;
            int r = ch >> LOGCPR;
            int c = ch & (CPR - 1);
            us8 v;
            if (BNIN == 3) {
                f32x4 lo = asf4(stg[2 * u]);
                f32x4 hi = asf4(stg[2 * u + 1]);
                us8 o;
                o[0] = f2bf(lo[0]); o[1] = f2bf(lo[1]); o[2] = f2bf(lo[2]); o[3] = f2bf(lo[3]);
                o[4] = f2bf(hi[0]); o[5] = f2bf(hi[1]); o[6] = f2bf(hi[2]); o[7] = f2bf(hi[3]);
                v = o;
            } else {
                v = stg[u];
                if (BNIN == 1 || BNIN == 2) {
                    us8 o;
                    #pragma unroll
                    for (int e = 0; e < 8; e++) {
                        float f = bf2f(v[e]) * sc8[e] + sh8[e];
                        f = (f > 0.f) ? f : f * negSlope;
                        o[e] = f2bf(f);
                    }
                    v = o;
                }
            }
            *(us8*)(abuf[buf] + (((r << LOGCPR) + (c ^ (r & 7))) * 8)) = v;
        }
    };

    us8 stgA[LPL2], stgB[LPL2];
    int s = s0;
    // prologue: abuf[0] <- s0; stgB <- s0+TT; stgA <- s0+2TT (in flight)
    stage_load(stgA, s);
    if (s + TT < mStrips) stage_load(stgB, s + TT);
    stage_write(0, stgA);
    if (s + 2 * TT < mStrips) stage_load(stgA, s + 2 * TT);
    __syncthreads();
    int cur = 0;

#define GEMM_STEP(STG)                                                                  \
    {                                                                                   \
        bf16x8 af[KC];                                                                  \
        _Pragma("unroll")                                                               \
        for (int kc = 0; kc < KC; kc++)                                                 \
            af[kc] = *(const bf16x8*)(abuf[cur] +                                       \
                     (((cl << LOGCPR) + ((kc * 4 + q) ^ (cl & 7))) * 8));               \
        if (s + TT < mStrips) stage_write(cur ^ 1, STG);                                \
        if (s + 3 * TT < mStrips) stage_load(STG, s + 3 * TT);                          \
        f32x4 acc[NT] = {};                                                             \
        _Pragma("unroll")                                                               \
        for (int kc = 0; kc < KC; kc++)                                                 \
            _Pragma("unroll")                                                           \
            for (int nt = 0; nt < NT; nt++)                                             \
                acc[nt] = __builtin_amdgcn_mfma_f32_16x16x32_bf16(af[kc], bf[nt][kc],   \
                                                                  acc[nt], 0, 0, 0);    \
        int rowBase = s * 16;                                                           \
        _Pragma("unroll")                                                               \
        for (int nt = 0; nt < NT; nt++) {                                               \
            _Pragma("unroll")                                                           \
            for (int r = 0; r < 4; r++) {                                               \
                float v = acc[nt][r];                                                   \
                long row = rowBase + q * 4 + r;                                         \
                C[row * N + colBase + nt * 16 + cl] = f2bf(v);                          \
                if (STATS) { ssum[nt] += v; ssq[nt] += v * v; }                         \
            }                                                                           \
        }                                                                               \
        __syncthreads();                                                                \
        s += TT; cur ^= 1;                                                              \
    }

    while (true) {
        GEMM_STEP(stgB);
        if (s >= mStrips) break;
        GEMM_STEP(stgA);
        if (s >= mStrips) break;
    }
#undef GEMM_STEP

    if (STATS) {
        #pragma unroll
        for (int nt = 0; nt < NT; nt++) {
            ssum[nt] += __shfl_xor(ssum[nt], 16, 64);
            ssum[nt] += __shfl_xor(ssum[nt], 32, 64);
            ssq[nt]  += __shfl_xor(ssq[nt], 16, 64);
            ssq[nt]  += __shfl_xor(ssq[nt], 32, 64);
        }
        if (q == 0) {
            #pragma unroll
            for (int nt = 0; nt < NT; nt++) {
                atomicAdd(&gsums[colBase + nt * 16 + cl], ssum[nt]);
                atomicAdd(&gsqs[colBase + nt * 16 + cl], ssq[nt]);
            }
        }
    }
}

// ======== fused setup: transpose weights, zero stats + degi/cursor (convert gone: CVT mode) ========
__global__ __launch_bounds__(256) void setup_all(
    const float* __restrict__ W0, const float* __restrict__ W1,
    const float* __restrict__ W2, const float* __restrict__ W3,
    const float* __restrict__ W4, const float* __restrict__ W5,
    ushort* __restrict__ WT,
    int* __restrict__ zeroInts, int nZero4, int nbZero,
    float* __restrict__ stats)
{
    int b = blockIdx.x;
    int tid = threadIdx.x;
    if (b < 768) {
        int seg = b >> 7;
        const float* W; int logK, dstBase, stride, kOff;
        switch (seg) {
            case 0: W = W0; logK = 7; dstBase = 0;      stride = 128; kOff = 0;   break;
            case 1: W = W1; logK = 8; dstBase = 32768;  stride = 256; kOff = 0;   break;
            case 2: W = W2; logK = 7; dstBase = 65536;  stride = 256; kOff = 0;   break;
            case 3: W = W3; logK = 7; dstBase = 65536;  stride = 256; kOff = 128; break;
            case 4: W = W4; logK = 8; dstBase = 131072; stride = 256; kOff = 0;   break;
            default:W = W5; logK = 8; dstBase = 163840; stride = 256; kOff = 0;   break;
        }
        int t = (b & 127) * 256 + tid;
        int N = 32768 >> logK;
        int k = t & ((1 << logK) - 1);
        int n = t >> logK;
        WT[(long)dstBase + (long)n * stride + kOff + k] = f2bf(W[(long)k * N + n]);
        return;
    }
    b -= 768;
    if (b < nbZero) {
        int t = b * 256 + tid;
        if (t < nZero4) *(int4*)&zeroInts[(long)t * 4] = make_int4(0, 0, 0, 0);
        return;
    }
    b -= nbZero;
    int t = b * 256 + tid;
    if (t < 512) *(float4*)&stats[(long)t * 4] = make_float4(0, 0, 0, 0);
}

// ======== BN params folded, fp32 in-place (final output, 128 ch) ========
__global__ __launch_bounds__(256) void bnact_f32(
    float* __restrict__ X,
    const float* __restrict__ sums, const float* __restrict__ sqs,
    const float* __restrict__ gamma, const float* __restrict__ beta, float invM,
    int nRows, float negSlope)
{
    __shared__ float ssc[128], ssh[128];
    int tid = threadIdx.x;
    if (tid < 128) {
        float mean = sums[tid] * invM;
        float var = sqs[tid] * invM - mean * mean;
        float sc = gamma[tid] * rsqrtf(var + BN_EPS);
        ssc[tid] = sc;
        ssh[tid] = beta[tid] - mean * sc;
    }
    __syncthreads();
    int cb = (tid * 4) & 127;
    float4 sc = *(const float4*)&ssc[cb];
    float4 sh = *(const float4*)&ssh[cb];
    int r0 = blockIdx.x * 8 + ((tid * 4) >> 7);
    int rstride = gridDim.x * 8;
    for (int row = r0; row < nRows; row += rstride) {
        float4 v = *(const float4*)&X[(long)row * 128 + cb];
        float a = v.x * sc.x + sh.x; a = (a > 0.f) ? a : a * negSlope;
        float b = v.y * sc.y + sh.y; b = (b > 0.f) ? b : b * negSlope;
        float d = v.z * sc.z + sh.z; d = (d > 0.f) ? d : d * negSlope;
        float e = v.w * sc.w + sh.w; e = (e > 0.f) ? e : e * negSlope;
        *(float4*)&X[(long)row * 128 + cb] = make_float4(a, b, d, e);
    }
}

// ======== column stats for final output (128 cols, register accum) ========
__global__ __launch_bounds__(256) void colstats128(
    const float* __restrict__ X, float* __restrict__ sums, float* __restrict__ sqs, int M)
{
    __shared__ float ss[128], sq[128];
    int tid = threadIdx.x;
    if (tid < 128) { ss[tid] = 0.f; sq[tid] = 0.f; }
    __syncthreads();
    int cg = tid & 31;
    int worker = (blockIdx.x << 3) | (tid >> 5);
    int totalW = gridDim.x << 3;
    float4 s4 = make_float4(0, 0, 0, 0), q4 = make_float4(0, 0, 0, 0);
    for (int r = worker; r < M; r += totalW) {
        float4 v = *(const float4*)&X[(long)r * 128 + cg * 4];
        s4.x += v.x; s4.y += v.y; s4.z += v.z; s4.w += v.w;
        q4.x += v.x * v.x; q4.y += v.y * v.y; q4.z += v.z * v.z; q4.w += v.w * v.w;
    }
    atomicAdd(&ss[cg * 4 + 0], s4.x); atomicAdd(&sq[cg * 4 + 0], q4.x);
    atomicAdd(&ss[cg * 4 + 1], s4.y); atomicAdd(&sq[cg * 4 + 1], q4.y);
    atomicAdd(&ss[cg * 4 + 2], s4.z); atomicAdd(&sq[cg * 4 + 2], q4.z);
    atomicAdd(&ss[cg * 4 + 3], s4.w); atomicAdd(&sq[cg * 4 + 3], q4.w);
    __syncthreads();
    if (tid < 128) { atomicAdd(&sums[tid], ss[tid]); atomicAdd(&sqs[tid], sq[tid]); }
}

// ======== CSR build ========
__global__ void degcount_kernel(const int* __restrict__ dst, int* __restrict__ degi, int E)
{
    int i = blockIdx.x * blockDim.x + threadIdx.x;
    if (i < E) atomicAdd(&degi[dst[i]], 1);
}

__global__ __launch_bounds__(256) void scan_block_sums(const int* __restrict__ degi,
                                                       int* __restrict__ partial, int n)
{
    __shared__ int s[256];
    int i = blockIdx.x * 256 + threadIdx.x;
    s[threadIdx.x] = (i < n) ? degi[i] : 0;
    __syncthreads();
    for (int off = 128; off > 0; off >>= 1) {
        if (threadIdx.x < off) s[threadIdx.x] += s[threadIdx.x + off];
        __syncthreads();
    }
    if (threadIdx.x == 0) partial[blockIdx.x] = s[0];
}

// scan_final also reduces the block-offset from raw per-block sums (scan_partials folded in)
__global__ __launch_bounds__(256) void scan_final(const int* __restrict__ degi,
                                                  const int* __restrict__ partial,
                                                  int* __restrict__ rowstart, int n, int nb)
{
    __shared__ int s[256];
    __shared__ int ps[256];
    int tid = threadIdx.x;
    ps[tid] = (tid < nb && tid < (int)blockIdx.x) ? partial[tid] : 0;
    __syncthreads();
    for (int off = 128; off > 0; off >>= 1) {
        if (tid < off) ps[tid] += ps[tid + off];
        __syncthreads();
    }
    int offset = ps[0];
    int i = blockIdx.x * 256 + tid;
    int v = (i < n) ? degi[i] : 0;
    s[tid] = v;
    __syncthreads();
    for (int off = 1; off < 256; off <<= 1) {
        int t = (tid >= off) ? s[tid - off] : 0;
        __syncthreads();
        s[tid] += t;
        __syncthreads();
    }
    if (i < n) rowstart[i] = offset + s[tid] - v;
}

__global__ void fillcsr_kernel(const int* __restrict__ src, const int* __restrict__ dst,
                               const int* __restrict__ rowstart, int* __restrict__ cursor,
                               int* __restrict__ csr, int E)
{
    int i = blockIdx.x * blockDim.x + threadIdx.x;
    if (i < E) {
        int d = dst[i];
        int p = atomicAdd(&cursor[d], 1);
        csr[rowstart[d] + p] = src[i];
    }
}

// ======== gather16_bn: 16-lane group per edge, BN_L1+ReLU applied inline on raw input ========
__global__ __launch_bounds__(256) void gather16_bn(
    const ushort* __restrict__ X, const int* __restrict__ rowstart,
    const int* __restrict__ degi, const int* __restrict__ csr,
    ushort* __restrict__ AGG, int nN,
    const float* __restrict__ isums, const float* __restrict__ isqs,
    const float* __restrict__ igam, const float* __restrict__ ibet, float invM)
{
    int wv = (blockIdx.x * blockDim.x + threadIdx.x) >> 6;
    int lane = threadIdx.x & 63;
    if (wv >= nN) return;
    int g = lane >> 4;        // edge slot 0..3
    int sc = lane & 15;       // 16-B chunk of row
    float sc8[8], sh8[8];
    {
        int cb = sc * 8;
        #pragma unroll
        for (int e = 0; e < 8; e++) {
            float mean = isums[cb + e] * invM;
            float var = isqs[cb + e] * invM - mean * mean;
            float s = igam[cb + e] * rsqrtf(var + BN_EPS);
            sc8[e] = s;
            sh8[e] = ibet[cb + e] - mean * s;
        }
    }
    int start = rowstart[wv], d = degi[wv];
    const ushort* Xc = X + sc * 8;
    float acc[8] = {};
    auto accbn8 = [&](us8 v) {
        #pragma unroll
        for (int e = 0; e < 8; e++)
            acc[e] += fmaxf(bf2f(v[e]) * sc8[e] + sh8[e], 0.f);
    };
    if (d > 0) {
        int dm = (d < 64) ? d : 64;
        int idx_l = csr[start + ((lane < dm) ? lane : (dm - 1))];
        int j = 0;
        for (; j + 8 <= dm; j += 8) {
            int i0 = __shfl(idx_l, j + g, 64);
            int i1 = __shfl(idx_l, j + 4 + g, 64);
            us8 v0 = *(const us8*)(Xc + (long)i0 * 128);
            us8 v1 = *(const us8*)(Xc + (long)i1 * 128);
            accbn8(v0);
            accbn8(v1);
        }
        if (j + 4 <= dm) {
            int i0 = __shfl(idx_l, j + g, 64);
            us8 v0 = *(const us8*)(Xc + (long)i0 * 128);
            accbn8(v0);
            j += 4;
        }
        int rem = dm - j;
        if (rem > 0) {
            int sl = j + ((g < rem) ? g : (rem - 1));
            int i0 = __shfl(idx_l, sl, 64);
            if (g < rem) {
                us8 v0 = *(const us8*)(Xc + (long)i0 * 128);
                accbn8(v0);
            }
        }
        for (int jj = 64; jj < d; jj += 4) {     // rare: degree > 64
            if (jj + g < d) {
                int i0 = csr[start + jj + g];
                us8 v0 = *(const us8*)(Xc + (long)i0 * 128);
                accbn8(v0);
            }
        }
    }
    #pragma unroll
    for (int e = 0; e < 8; e++) {
        acc[e] += __shfl_xor(acc[e], 16, 64);
        acc[e] += __shfl_xor(acc[e], 32, 64);
    }
    if (g == 0) {
        float inv = 1.f / fmaxf((float)d, 1.f);
        us8 o;
        #pragma unroll
        for (int e = 0; e < 8; e++) o[e] = f2bf(acc[e] * inv);
        *(us8*)(AGG + (long)wv * 128 + sc * 8) = o;
    }
}

// fused gather2: out = mean(Z[src, 0:128]) + Z[dst, 128:256]  (fp32 out, 128 cols)
__device__ __forceinline__ void acc8(float acc[8], us8 v) {
    #pragma unroll
    for (int e = 0; e < 8; e++) acc[e] += bf2f(v[e]);
}

__global__ __launch_bounds__(256) void gather16_fuse(
    const ushort* __restrict__ Z, const int* __restrict__ rowstart,
    const int* __restrict__ degi, const int* __restrict__ csr,
    float* __restrict__ O, int nN)
{
    int wv = (blockIdx.x * blockDim.x + threadIdx.x) >> 6;
    int lane = threadIdx.x & 63;
    if (wv >= nN) return;
    int g = lane >> 4;
    int sc = lane & 15;
    int start = rowstart[wv], d = degi[wv];
    const ushort* Zc = Z + sc * 8;
    us8 selfv = *(const us8*)(Zc + (long)wv * 256 + 128);   // independent, issued early
    float acc[8] = {};
    if (d > 0) {
        int dm = (d < 64) ? d : 64;
        int idx_l = csr[start + ((lane < dm) ? lane : (dm - 1))];
        int j = 0;
        for (; j + 8 <= dm; j += 8) {
            int i0 = __shfl(idx_l, j + g, 64);
            int i1 = __shfl(idx_l, j + 4 + g, 64);
            us8 v0 = *(const us8*)(Zc + (long)i0 * 256);
            us8 v1 = *(const us8*)(Zc + (long)i1 * 256);
            acc8(acc, v0);
            acc8(acc, v1);
        }
        if (j + 4 <= dm) {
            int i0 = __shfl(idx_l, j + g, 64);
            us8 v0 = *(const us8*)(Zc + (long)i0 * 256);
            acc8(acc, v0);
            j += 4;
        }
        int rem = dm - j;
        if (rem > 0) {
            int sl = j + ((g < rem) ? g : (rem - 1));
            int i0 = __shfl(idx_l, sl, 64);
            if (g < rem) {
                us8 v0 = *(const us8*)(Zc + (long)i0 * 256);
                acc8(acc, v0);
            }
        }
        for (int jj = 64; jj < d; jj += 4) {
            if (jj + g < d) {
                int i0 = csr[start + jj + g];
                us8 v0 = *(const us8*)(Zc + (long)i0 * 256);
                acc8(acc, v0);
            }
        }
    }
    #pragma unroll
    for (int e = 0; e < 8; e++) {
        acc[e] += __shfl_xor(acc[e], 16, 64);
        acc[e] += __shfl_xor(acc[e], 32, 64);
    }
    if (g == 0) {
        float inv = 1.f / fmaxf((float)d, 1.f);
        float r[8];
        #pragma unroll
        for (int e = 0; e < 8; e++) r[e] = acc[e] * inv + bf2f(selfv[e]);
        float* op = O + (long)wv * 128 + sc * 8;
        *(float4*)op = make_float4(r[0], r[1], r[2], r[3]);
        *(float4*)(op + 4) = make_float4(r[4], r[5], r[6], r[7]);
    }
}

extern "C" void kernel_launch(void* const* d_in, const int* in_sizes, int n_in,
                              void* d_out, int out_size, void* d_ws, size_t ws_size,
                              hipStream_t stream)
{
    const float* nodes = (const float*)d_in[0];
    const int*   src   = (const int*)d_in[1];
    const int*   dst   = (const int*)d_in[2];
    const float* Wf1   = (const float*)d_in[3];
    const float* gf1   = (const float*)d_in[5];
    const float* bef1  = (const float*)d_in[6];
    const float* Wf2   = (const float*)d_in[7];
    const float* gf2   = (const float*)d_in[9];
    const float* bef2  = (const float*)d_in[10];
    const float* Ws1   = (const float*)d_in[11];
    const float* Wn1   = (const float*)d_in[12];
    const float* gs1   = (const float*)d_in[14];
    const float* bs1   = (const float*)d_in[15];
    const float* Ws2   = (const float*)d_in[16];
    const float* Wn2   = (const float*)d_in[17];
    const float* gs2   = (const float*)d_in[19];
    const float* bs2   = (const float*)d_in[20];
    // pre-BN biases (bf1,bf2,b1,b2) cancel under BatchNorm -> skipped

    int nN = in_sizes[0] / DIN;   // 50000
    int nE = in_sizes[1];         // 600000
    float* out = (float*)d_out;
    int mStrips = nN / 16;        // 3125 (exact)
    float invM = 1.0f / nN;

    // ---- workspace (identical layout to passing version) ----
    ushort* PRE = (ushort*)d_ws;                      // nN*256 bf16 raw GEMM out
    ushort* BF1 = PRE + (size_t)nN * 256;             // nN*256 bf16 (FF2 raw, compact 128)
    ushort* BF2 = BF1 + (size_t)nN * 256;             // nN*256 bf16 (AGG compact / Z)
    float* stats = (float*)(BF2 + (size_t)nN * 256);  // 2048 floats, 4 layer-regions
    float* scale = stats + 2048;                      // 256 (unused, kept for layout)
    float* shift = scale + 256;                       // 256 (unused, kept for layout)
    ushort* WT   = (ushort*)(shift + 256);            // 196608 shorts
    int* degi     = (int*)(WT + 196608);              // nN
    int* cursor   = degi + nN;                        // nN (adjacent: zeroed together)
    int* rowstart = cursor + nN;                      // nN
    int* partial  = rowstart + nN;                    // 256
    int* csr      = partial + 256;                    // nE

    ushort* Wf1T = WT;
    ushort* Wf2T = WT + 32768;
    ushort* Wc1T = WT + 65536;
    ushort* Wc2T = WT + 131072;
    ushort* AGG  = BF2;                               // compact nN*128 agg buffer

    dim3 blk(256);
    auto cdiv = [](int a, int b) { return (a + b - 1) / b; };
    int nScanBlocks = cdiv(nN, 256);                  // 196 (must be <= 256)

    // ---- fused setup: weight transpose + zero stats/degi/cursor (node convert now in FF1) ----
    int nZero4 = (2 * nN) / 4;
    int nbZero = cdiv(nZero4, 256);
    setup_all<<<dim3(768 + nbZero + 2), blk, 0, stream>>>(
        Wf1, Wf2, Ws1, Wn1, Wn2, Ws2, WT,
        degi, nZero4, nbZero, stats);

    // ---- CSR build ----
    degcount_kernel<<<dim3(cdiv(nE, 256)), blk, 0, stream>>>(dst, degi, nE);
    scan_block_sums<<<dim3(nScanBlocks), blk, 0, stream>>>(degi, partial, nN);
    scan_final<<<dim3(nScanBlocks), blk, 0, stream>>>(degi, partial, rowstart, nN, nScanBlocks);
    fillcsr_kernel<<<dim3(cdiv(nE, 256)), blk, 0, stream>>>(src, dst, rowstart, cursor, csr, nE);

    // ---- FF1: PRE = f2bf(nodes) @ Wf1T (BNIN=3 CVT staging; K=128, N=256, stats->L0) ----
    gemm_lds<4, 4, 0, 1, 3><<<dim3(512), blk, 0, stream>>>(
        (const ushort*)nodes, Wf1T, PRE, mStrips, 256, stats, stats + 256,
        nullptr, nullptr, nullptr, nullptr, 0.f, 0.f, nullptr);

    // ---- FF2: BF1 = act(BN_L0(PRE)) @ Wf2T (BNIN=1; K=256, N=128 compact, stats->L1) ----
    gemm_lds<8, 2, 0, 1, 1><<<dim3(512), blk, 0, stream>>>(
        PRE, Wf2T, BF1, mStrips, 128, stats + 512, stats + 768,
        stats, stats + 256, gf1, bef1, invM, 0.0f, nullptr);

    // ---- gather1 (BN fused): AGG = mean-gather(ReLU(BN_L1(BF1))) ----
    gather16_bn<<<dim3(cdiv(nN * 64, 256)), blk, 0, stream>>>(
        BF1, rowstart, degi, csr, AGG, nN,
        stats + 512, stats + 768, gf2, bef2, invM);

    // ---- SAGE1: PRE = [ReLU(BN_L1(BF1)) | AGG] @ [Ws1;Wn1] (BNIN=2 dual-source;
    //      K=256, N=256, stats->L2) ----
    gemm_lds<8, 4, 0, 1, 2><<<dim3(512), blk, 0, stream>>>(
        BF1, Wc1T, PRE, mStrips, 256, stats + 1024, stats + 1280,
        stats + 512, stats + 768, gf2, bef2, invM, 0.0f, AGG);

    // ---- SAGE2: BF2 = act(BN_L2(PRE)) @ [Wn2|Ws2] (BNIN=1; K=256, N=256, NT=2, no stats) ----
    gemm_lds<8, 2, 1, 0, 1><<<dim3(512), blk, 0, stream>>>(
        PRE, Wc2T, BF2, mStrips, 256, nullptr, nullptr,
        stats + 1024, stats + 1280, gs1, bs1, invM, 0.01f, nullptr);

    // ---- gather_fuse -> out(fp32) ----
    gather16_fuse<<<dim3(cdiv(nN * 64, 256)), blk, 0, stream>>>(BF2, rowstart, degi, csr, out, nN);

    // ---- final: colstats -> fused BN+LReLU on out ----
    colstats128<<<dim3(120), blk, 0, stream>>>(out, stats + 1536, stats + 1792, nN);
    bnact_f32<<<dim3(2048), blk, 0, stream>>>(out, stats + 1536, stats + 1792, gs2, bs2, invM,
                                              nN, 0.01f);
}

// Round 13
// 343.120 us; speedup vs baseline: 1.0383x; 1.0037x over previous
//
#include <hip/hip_runtime.h>

#define DIN 128
#define BN_EPS 1e-5f

typedef __attribute__((ext_vector_type(8))) short bf16x8;
typedef __attribute__((ext_vector_type(8))) unsigned short us8;
typedef __attribute__((ext_vector_type(4))) float f32x4;

__device__ __forceinline__ ushort f2bf(float f) {
    unsigned u = __float_as_uint(f);
    u += 0x7fffu + ((u >> 16) & 1u);
    return (ushort)(u >> 16);
}
__device__ __forceinline__ float bf2f(ushort h) {
    return __uint_as_float(((unsigned)h) << 16);
}
__device__ __forceinline__ f32x4 asf4(us8 v) {
    union { us8 u; f32x4 f; } x; x.u = v; return x.f;
}

// ======== LDS-shared streaming GEMM (R12-best config) ========
// Block-shared A strip, double-buffered LDS, depth-2 prefetch, 1 barrier/strip,
// 512-block grids. Staging transform modes:
//   BNIN=0: plain bf16 copy
//   BNIN=1: BN+act of previous layer applied during staging (reads raw PRE)
//   BNIN=2: dual-source [h|agg] with BN+ReLU on h-half, identity on agg-half
//   BNIN=3: CVT - stage directly from fp32 source, f2bf convert in staging
// R13: SAGE2 moved NT=2/LOGNG=1 -> NT=4/LOGNG=0 (stages A once, not twice; same
// 128-VGPR shape as SAGE1, proven in R8 counters).
template<int KC, int NT, int LOGNG, int STATS, int BNIN>
__global__ __launch_bounds__(256) void gemm_lds(
    const ushort* __restrict__ A, const ushort* __restrict__ BT,
    ushort* __restrict__ C, int mStrips, int N,
    float* __restrict__ gsums, float* __restrict__ gsqs,
    const float* __restrict__ isums, const float* __restrict__ isqs,
    const float* __restrict__ igam, const float* __restrict__ ibet,
    float invM, float negSlope,
    const ushort* __restrict__ A2)
{
    constexpr int K = KC * 32;           // K in shorts
    constexpr int CPR = KC * 4;          // 16B chunks per row
    constexpr int LOGCPR = (KC == 4) ? 4 : 5;
    constexpr int LPL = KC / 4;          // staging chunks per lane (1 or 2)
    constexpr int LPL2 = (BNIN == 3) ? 2 * LPL : LPL;   // regs (CVT: 2 us8 per chunk)
    __shared__ ushort abuf[2][16 * K];   // double-buffered strip (2x 4/8 KB)

    int tid = threadIdx.x;
    int lane = tid & 63;
    int w = tid >> 6;
    int cl = lane & 15, q = lane >> 4;
    int grp = blockIdx.x & ((1 << LOGNG) - 1);
    int s0 = blockIdx.x >> LOGNG;
    int TT = gridDim.x >> LOGNG;         // strip stride
    int colBase = grp * (4 * 16 * NT) + w * (16 * NT);
    int chBase = w * (16 * KC);          // this wave's staging chunk range

    // B fragments: loaded once (weights L2-resident)
    bf16x8 bf[NT][KC];
    #pragma unroll
    for (int nt = 0; nt < NT; nt++) {
        const ushort* bp = BT + (long)(colBase + nt * 16 + cl) * K + q * 8;
        #pragma unroll
        for (int kc = 0; kc < KC; kc++)
            bf[nt][kc] = *(const bf16x8*)(bp + kc * 32);
    }

    // BN-in-staging params: the lane's staging chunks share one K-column
    float sc8[8], sh8[8];
    const ushort* dsrc = A;              // BNIN==2: per-lane source base
    int dcol = 0;
    if (BNIN == 1) {
        int cb = ((chBase + lane) & (CPR - 1)) * 8;
        #pragma unroll
        for (int e = 0; e < 8; e++) {
            float mean = isums[cb + e] * invM;
            float var = isqs[cb + e] * invM - mean * mean;
            float s = igam[cb + e] * rsqrtf(var + BN_EPS);
            sc8[e] = s;
            sh8[e] = ibet[cb + e] - mean * s;
        }
    } else if (BNIN == 2) {
        int c = (chBase + lane) & (CPR - 1);
        dsrc = (c < 16) ? A : A2;
        dcol = (c & 15) * 8;
        if (c < 16) {
            int cb = c * 8;
            #pragma unroll
            for (int e = 0; e < 8; e++) {
                float mean = isums[cb + e] * invM;
                float var = isqs[cb + e] * invM - mean * mean;
                float s = igam[cb + e] * rsqrtf(var + BN_EPS);
                sc8[e] = s;
                sh8[e] = ibet[cb + e] - mean * s;
            }
        } else {
            #pragma unroll
            for (int e = 0; e < 8; e++) { sc8[e] = 1.0f; sh8[e] = 0.0f; }
        }
    }

    float ssum[NT], ssq[NT];
    #pragma unroll
    for (int nt = 0; nt < NT; nt++) { ssum[nt] = 0.f; ssq[nt] = 0.f; }

    auto stage_load = [&](us8 (&stg)[LPL2], int strip) {
        if (BNIN == 3) {
            const float* Af = (const float*)A;
            #pragma unroll
            for (int u = 0; u < LPL; u++) {
                int ch = chBase + u * 64 + lane;
                int r = ch >> LOGCPR;
                int c = ch & (CPR - 1);
                const float* p = Af + (long)(strip * 16 + r) * K + c * 8;
                stg[2 * u]     = *(const us8*)p;
                stg[2 * u + 1] = *(const us8*)(p + 4);
            }
        } else if (BNIN == 2) {
            #pragma unroll
            for (int u = 0; u < LPL; u++) {
                int r = (chBase + u * 64 + lane) >> LOGCPR;
                stg[u] = *(const us8*)(dsrc + ((long)(strip * 16 + r)) * 128 + dcol);
            }
        } else {
            const ushort* As = A + (long)strip * 16 * K;
            #pragma unroll
            for (int u = 0; u < LPL; u++)
                stg[u] = *(const us8*)(As + (chBase + u * 64 + lane) * 8);
        }
    };
    auto stage_write = [&](int buf, us8 (&stg)[LPL2]) {
        #pragma unroll
        for (int u = 0; u < LPL; u++) {
            int ch = chBase + u * 64 + lane;
            int r = ch >> LOGCPR;
            int c = ch & (CPR - 1);
            us8 v;
            if (BNIN == 3) {
                f32x4 lo = asf4(stg[2 * u]);
                f32x4 hi = asf4(stg[2 * u + 1]);
                us8 o;
                o[0] = f2bf(lo[0]); o[1] = f2bf(lo[1]); o[2] = f2bf(lo[2]); o[3] = f2bf(lo[3]);
                o[4] = f2bf(hi[0]); o[5] = f2bf(hi[1]); o[6] = f2bf(hi[2]); o[7] = f2bf(hi[3]);
                v = o;
            } else {
                v = stg[u];
                if (BNIN == 1 || BNIN == 2) {
                    us8 o;
                    #pragma unroll
                    for (int e = 0; e < 8; e++) {
                        float f = bf2f(v[e]) * sc8[e] + sh8[e];
                        f = (f > 0.f) ? f : f * negSlope;
                        o[e] = f2bf(f);
                    }
                    v = o;
                }
            }
            *(us8*)(abuf[buf] + (((r << LOGCPR) + (c ^ (r & 7))) * 8)) = v;
        }
    };

    us8 stgA[LPL2], stgB[LPL2];
    int s = s0;
    // prologue: abuf[0] <- s0; stgB <- s0+TT; stgA <- s0+2TT (in flight)
    stage_load(stgA, s);
    if (s + TT < mStrips) stage_load(stgB, s + TT);
    stage_write(0, stgA);
    if (s + 2 * TT < mStrips) stage_load(stgA, s + 2 * TT);
    __syncthreads();
    int cur = 0;

#define GEMM_STEP(STG)                                                                  \
    {                                                                                   \
        bf16x8 af[KC];                                                                  \
        _Pragma("unroll")                                                               \
        for (int kc = 0; kc < KC; kc++)                                                 \
            af[kc] = *(const bf16x8*)(abuf[cur] +                                       \
                     (((cl << LOGCPR) + ((kc * 4 + q) ^ (cl & 7))) * 8));               \
        if (s + TT < mStrips) stage_write(cur ^ 1, STG);                                \
        if (s + 3 * TT < mStrips) stage_load(STG, s + 3 * TT);                          \
        f32x4 acc[NT] = {};                                                             \
        _Pragma("unroll")                                                               \
        for (int kc = 0; kc < KC; kc++)                                                 \
            _Pragma("unroll")                                                           \
            for (int nt = 0; nt < NT; nt++)                                             \
                acc[nt] = __builtin_amdgcn_mfma_f32_16x16x32_bf16(af[kc], bf[nt][kc],   \
                                                                  acc[nt], 0, 0, 0);    \
        int rowBase = s * 16;                                                           \
        _Pragma("unroll")                                                               \
        for (int nt = 0; nt < NT; nt++) {                                               \
            _Pragma("unroll")                                                           \
            for (int r = 0; r < 4; r++) {                                               \
                float v = acc[nt][r];                                                   \
                long row = rowBase + q * 4 + r;                                         \
                C[row * N + colBase + nt * 16 + cl] = f2bf(v);                          \
                if (STATS) { ssum[nt] += v; ssq[nt] += v * v; }                         \
            }                                                                           \
        }                                                                               \
        __syncthreads();                                                                \
        s += TT; cur ^= 1;                                                              \
    }

    while (true) {
        GEMM_STEP(stgB);
        if (s >= mStrips) break;
        GEMM_STEP(stgA);
        if (s >= mStrips) break;
    }
#undef GEMM_STEP

    if (STATS) {
        #pragma unroll
        for (int nt = 0; nt < NT; nt++) {
            ssum[nt] += __shfl_xor(ssum[nt], 16, 64);
            ssum[nt] += __shfl_xor(ssum[nt], 32, 64);
            ssq[nt]  += __shfl_xor(ssq[nt], 16, 64);
            ssq[nt]  += __shfl_xor(ssq[nt], 32, 64);
        }
        if (q == 0) {
            #pragma unroll
            for (int nt = 0; nt < NT; nt++) {
                atomicAdd(&gsums[colBase + nt * 16 + cl], ssum[nt]);
                atomicAdd(&gsqs[colBase + nt * 16 + cl], ssq[nt]);
            }
        }
    }
}

// ======== fused setup: transpose weights, zero stats + degi/cursor ========
__global__ __launch_bounds__(256) void setup_all(
    const float* __restrict__ W0, const float* __restrict__ W1,
    const float* __restrict__ W2, const float* __restrict__ W3,
    const float* __restrict__ W4, const float* __restrict__ W5,
    ushort* __restrict__ WT,
    int* __restrict__ zeroInts, int nZero4, int nbZero,
    float* __restrict__ stats)
{
    int b = blockIdx.x;
    int tid = threadIdx.x;
    if (b < 768) {
        int seg = b >> 7;
        const float* W; int logK, dstBase, stride, kOff;
        switch (seg) {
            case 0: W = W0; logK = 7; dstBase = 0;      stride = 128; kOff = 0;   break;
            case 1: W = W1; logK = 8; dstBase = 32768;  stride = 256; kOff = 0;   break;
            case 2: W = W2; logK = 7; dstBase = 65536;  stride = 256; kOff = 0;   break;
            case 3: W = W3; logK = 7; dstBase = 65536;  stride = 256; kOff = 128; break;
            case 4: W = W4; logK = 8; dstBase = 131072; stride = 256; kOff = 0;   break;
            default:W = W5; logK = 8; dstBase = 163840; stride = 256; kOff = 0;   break;
        }
        int t = (b & 127) * 256 + tid;
        int N = 32768 >> logK;
        int k = t & ((1 << logK) - 1);
        int n = t >> logK;
        WT[(long)dstBase + (long)n * stride + kOff + k] = f2bf(W[(long)k * N + n]);
        return;
    }
    b -= 768;
    if (b < nbZero) {
        int t = b * 256 + tid;
        if (t < nZero4) *(int4*)&zeroInts[(long)t * 4] = make_int4(0, 0, 0, 0);
        return;
    }
    b -= nbZero;
    int t = b * 256 + tid;
    if (t < 512) *(float4*)&stats[(long)t * 4] = make_float4(0, 0, 0, 0);
}

// ======== BN params folded, fp32 in-place (final output, 128 ch) ========
__global__ __launch_bounds__(256) void bnact_f32(
    float* __restrict__ X,
    const float* __restrict__ sums, const float* __restrict__ sqs,
    const float* __restrict__ gamma, const float* __restrict__ beta, float invM,
    int nRows, float negSlope)
{
    __shared__ float ssc[128], ssh[128];
    int tid = threadIdx.x;
    if (tid < 128) {
        float mean = sums[tid] * invM;
        float var = sqs[tid] * invM - mean * mean;
        float sc = gamma[tid] * rsqrtf(var + BN_EPS);
        ssc[tid] = sc;
        ssh[tid] = beta[tid] - mean * sc;
    }
    __syncthreads();
    int cb = (tid * 4) & 127;
    float4 sc = *(const float4*)&ssc[cb];
    float4 sh = *(const float4*)&ssh[cb];
    int r0 = blockIdx.x * 8 + ((tid * 4) >> 7);
    int rstride = gridDim.x * 8;
    for (int row = r0; row < nRows; row += rstride) {
        float4 v = *(const float4*)&X[(long)row * 128 + cb];
        float a = v.x * sc.x + sh.x; a = (a > 0.f) ? a : a * negSlope;
        float b = v.y * sc.y + sh.y; b = (b > 0.f) ? b : b * negSlope;
        float d = v.z * sc.z + sh.z; d = (d > 0.f) ? d : d * negSlope;
        float e = v.w * sc.w + sh.w; e = (e > 0.f) ? e : e * negSlope;
        *(float4*)&X[(long)row * 128 + cb] = make_float4(a, b, d, e);
    }
}

// ======== column stats for final output (128 cols, register accum) ========
__global__ __launch_bounds__(256) void colstats128(
    const float* __restrict__ X, float* __restrict__ sums, float* __restrict__ sqs, int M)
{
    __shared__ float ss[128], sq[128];
    int tid = threadIdx.x;
    if (tid < 128) { ss[tid] = 0.f; sq[tid] = 0.f; }
    __syncthreads();
    int cg = tid & 31;
    int worker = (blockIdx.x << 3) | (tid >> 5);
    int totalW = gridDim.x << 3;
    float4 s4 = make_float4(0, 0, 0, 0), q4 = make_float4(0, 0, 0, 0);
    for (int r = worker; r < M; r += totalW) {
        float4 v = *(const float4*)&X[(long)r * 128 + cg * 4];
        s4.x += v.x; s4.y += v.y; s4.z += v.z; s4.w += v.w;
        q4.x += v.x * v.x; q4.y += v.y * v.y; q4.z += v.z * v.z; q4.w += v.w * v.w;
    }
    atomicAdd(&ss[cg * 4 + 0], s4.x); atomicAdd(&sq[cg * 4 + 0], q4.x);
    atomicAdd(&ss[cg * 4 + 1], s4.y); atomicAdd(&sq[cg * 4 + 1], q4.y);
    atomicAdd(&ss[cg * 4 + 2], s4.z); atomicAdd(&sq[cg * 4 + 2], q4.z);
    atomicAdd(&ss[cg * 4 + 3], s4.w); atomicAdd(&sq[cg * 4 + 3], q4.w);
    __syncthreads();
    if (tid < 128) { atomicAdd(&sums[tid], ss[tid]); atomicAdd(&sqs[tid], sq[tid]); }
}

// ======== CSR build ========
__global__ void degcount_kernel(const int* __restrict__ dst, int* __restrict__ degi, int E)
{
    int i = blockIdx.x * blockDim.x + threadIdx.x;
    if (i < E) atomicAdd(&degi[dst[i]], 1);
}

__global__ __launch_bounds__(256) void scan_block_sums(const int* __restrict__ degi,
                                                       int* __restrict__ partial, int n)
{
    __shared__ int s[256];
    int i = blockIdx.x * 256 + threadIdx.x;
    s[threadIdx.x] = (i < n) ? degi[i] : 0;
    __syncthreads();
    for (int off = 128; off > 0; off >>= 1) {
        if (threadIdx.x < off) s[threadIdx.x] += s[threadIdx.x + off];
        __syncthreads();
    }
    if (threadIdx.x == 0) partial[blockIdx.x] = s[0];
}

// scan_final also reduces the block-offset from raw per-block sums (scan_partials folded in)
__global__ __launch_bounds__(256) void scan_final(const int* __restrict__ degi,
                                                  const int* __restrict__ partial,
                                                  int* __restrict__ rowstart, int n, int nb)
{
    __shared__ int s[256];
    __shared__ int ps[256];
    int tid = threadIdx.x;
    ps[tid] = (tid < nb && tid < (int)blockIdx.x) ? partial[tid] : 0;
    __syncthreads();
    for (int off = 128; off > 0; off >>= 1) {
        if (tid < off) ps[tid] += ps[tid + off];
        __syncthreads();
    }
    int offset = ps[0];
    int i = blockIdx.x * 256 + tid;
    int v = (i < n) ? degi[i] : 0;
    s[tid] = v;
    __syncthreads();
    for (int off = 1; off < 256; off <<= 1) {
        int t = (tid >= off) ? s[tid - off] : 0;
        __syncthreads();
        s[tid] += t;
        __syncthreads();
    }
    if (i < n) rowstart[i] = offset + s[tid] - v;
}

__global__ void fillcsr_kernel(const int* __restrict__ src, const int* __restrict__ dst,
                               const int* __restrict__ rowstart, int* __restrict__ cursor,
                               int* __restrict__ csr, int E)
{
    int i = blockIdx.x * blockDim.x + threadIdx.x;
    if (i < E) {
        int d = dst[i];
        int p = atomicAdd(&cursor[d], 1);
        csr[rowstart[d] + p] = src[i];
    }
}

// ======== gather16_bn: 16-lane group per edge, BN_L1+ReLU applied inline on raw input ========
__global__ __launch_bounds__(256) void gather16_bn(
    const ushort* __restrict__ X, const int* __restrict__ rowstart,
    const int* __restrict__ degi, const int* __restrict__ csr,
    ushort* __restrict__ AGG, int nN,
    const float* __restrict__ isums, const float* __restrict__ isqs,
    const float* __restrict__ igam, const float* __restrict__ ibet, float invM)
{
    int wv = (blockIdx.x * blockDim.x + threadIdx.x) >> 6;
    int lane = threadIdx.x & 63;
    if (wv >= nN) return;
    int g = lane >> 4;        // edge slot 0..3
    int sc = lane & 15;       // 16-B chunk of row
    float sc8[8], sh8[8];
    {
        int cb = sc * 8;
        #pragma unroll
        for (int e = 0; e < 8; e++) {
            float mean = isums[cb + e] * invM;
            float var = isqs[cb + e] * invM - mean * mean;
            float s = igam[cb + e] * rsqrtf(var + BN_EPS);
            sc8[e] = s;
            sh8[e] = ibet[cb + e] - mean * s;
        }
    }
    int start = rowstart[wv], d = degi[wv];
    const ushort* Xc = X + sc * 8;
    float acc[8] = {};
    auto accbn8 = [&](us8 v) {
        #pragma unroll
        for (int e = 0; e < 8; e++)
            acc[e] += fmaxf(bf2f(v[e]) * sc8[e] + sh8[e], 0.f);
    };
    if (d > 0) {
        int dm = (d < 64) ? d : 64;
        int idx_l = csr[start + ((lane < dm) ? lane : (dm - 1))];
        int j = 0;
        for (; j + 8 <= dm; j += 8) {
            int i0 = __shfl(idx_l, j + g, 64);
            int i1 = __shfl(idx_l, j + 4 + g, 64);
            us8 v0 = *(const us8*)(Xc + (long)i0 * 128);
            us8 v1 = *(const us8*)(Xc + (long)i1 * 128);
            accbn8(v0);
            accbn8(v1);
        }
        if (j + 4 <= dm) {
            int i0 = __shfl(idx_l, j + g, 64);
            us8 v0 = *(const us8*)(Xc + (long)i0 * 128);
            accbn8(v0);
            j += 4;
        }
        int rem = dm - j;
        if (rem > 0) {
            int sl = j + ((g < rem) ? g : (rem - 1));
            int i0 = __shfl(idx_l, sl, 64);
            if (g < rem) {
                us8 v0 = *(const us8*)(Xc + (long)i0 * 128);
                accbn8(v0);
            }
        }
        for (int jj = 64; jj < d; jj += 4) {     // rare: degree > 64
            if (jj + g < d) {
                int i0 = csr[start + jj + g];
                us8 v0 = *(const us8*)(Xc + (long)i0 * 128);
                accbn8(v0);
            }
        }
    }
    #pragma unroll
    for (int e = 0; e < 8; e++) {
        acc[e] += __shfl_xor(acc[e], 16, 64);
        acc[e] += __shfl_xor(acc[e], 32, 64);
    }
    if (g == 0) {
        float inv = 1.f / fmaxf((float)d, 1.f);
        us8 o;
        #pragma unroll
        for (int e = 0; e < 8; e++) o[e] = f2bf(acc[e] * inv);
        *(us8*)(AGG + (long)wv * 128 + sc * 8) = o;
    }
}

// fused gather2: out = mean(Z[src, 0:128]) + Z[dst, 128:256]  (fp32 out, 128 cols)
__device__ __forceinline__ void acc8(float acc[8], us8 v) {
    #pragma unroll
    for (int e = 0; e < 8; e++) acc[e] += bf2f(v[e]);
}

__global__ __launch_bounds__(256) void gather16_fuse(
    const ushort* __restrict__ Z, const int* __restrict__ rowstart,
    const int* __restrict__ degi, const int* __restrict__ csr,
    float* __restrict__ O, int nN)
{
    int wv = (blockIdx.x * blockDim.x + threadIdx.x) >> 6;
    int lane = threadIdx.x & 63;
    if (wv >= nN) return;
    int g = lane >> 4;
    int sc = lane & 15;
    int start = rowstart[wv], d = degi[wv];
    const ushort* Zc = Z + sc * 8;
    us8 selfv = *(const us8*)(Zc + (long)wv * 256 + 128);   // independent, issued early
    float acc[8] = {};
    if (d > 0) {
        int dm = (d < 64) ? d : 64;
        int idx_l = csr[start + ((lane < dm) ? lane : (dm - 1))];
        int j = 0;
        for (; j + 8 <= dm; j += 8) {
            int i0 = __shfl(idx_l, j + g, 64);
            int i1 = __shfl(idx_l, j + 4 + g, 64);
            us8 v0 = *(const us8*)(Zc + (long)i0 * 256);
            us8 v1 = *(const us8*)(Zc + (long)i1 * 256);
            acc8(acc, v0);
            acc8(acc, v1);
        }
        if (j + 4 <= dm) {
            int i0 = __shfl(idx_l, j + g, 64);
            us8 v0 = *(const us8*)(Zc + (long)i0 * 256);
            acc8(acc, v0);
            j += 4;
        }
        int rem = dm - j;
        if (rem > 0) {
            int sl = j + ((g < rem) ? g : (rem - 1));
            int i0 = __shfl(idx_l, sl, 64);
            if (g < rem) {
                us8 v0 = *(const us8*)(Zc + (long)i0 * 256);
                acc8(acc, v0);
            }
        }
        for (int jj = 64; jj < d; jj += 4) {
            if (jj + g < d) {
                int i0 = csr[start + jj + g];
                us8 v0 = *(const us8*)(Zc + (long)i0 * 256);
                acc8(acc, v0);
            }
        }
    }
    #pragma unroll
    for (int e = 0; e < 8; e++) {
        acc[e] += __shfl_xor(acc[e], 16, 64);
        acc[e] += __shfl_xor(acc[e], 32, 64);
    }
    if (g == 0) {
        float inv = 1.f / fmaxf((float)d, 1.f);
        float r[8];
        #pragma unroll
        for (int e = 0; e < 8; e++) r[e] = acc[e] * inv + bf2f(selfv[e]);
        float* op = O + (long)wv * 128 + sc * 8;
        *(float4*)op = make_float4(r[0], r[1], r[2], r[3]);
        *(float4*)(op + 4) = make_float4(r[4], r[5], r[6], r[7]);
    }
}

extern "C" void kernel_launch(void* const* d_in, const int* in_sizes, int n_in,
                              void* d_out, int out_size, void* d_ws, size_t ws_size,
                              hipStream_t stream)
{
    const float* nodes = (const float*)d_in[0];
    const int*   src   = (const int*)d_in[1];
    const int*   dst   = (const int*)d_in[2];
    const float* Wf1   = (const float*)d_in[3];
    const float* gf1   = (const float*)d_in[5];
    const float* bef1  = (const float*)d_in[6];
    const float* Wf2   = (const float*)d_in[7];
    const float* gf2   = (const float*)d_in[9];
    const float* bef2  = (const float*)d_in[10];
    const float* Ws1   = (const float*)d_in[11];
    const float* Wn1   = (const float*)d_in[12];
    const float* gs1   = (const float*)d_in[14];
    const float* bs1   = (const float*)d_in[15];
    const float* Ws2   = (const float*)d_in[16];
    const float* Wn2   = (const float*)d_in[17];
    const float* gs2   = (const float*)d_in[19];
    const float* bs2   = (const float*)d_in[20];
    // pre-BN biases (bf1,bf2,b1,b2) cancel under BatchNorm -> skipped

    int nN = in_sizes[0] / DIN;   // 50000
    int nE = in_sizes[1];         // 600000
    float* out = (float*)d_out;
    int mStrips = nN / 16;        // 3125 (exact)
    float invM = 1.0f / nN;

    // ---- workspace (identical layout to passing version) ----
    ushort* PRE = (ushort*)d_ws;                      // nN*256 bf16 raw GEMM out
    ushort* BF1 = PRE + (size_t)nN * 256;             // nN*256 bf16 (FF2 raw, compact 128)
    ushort* BF2 = BF1 + (size_t)nN * 256;             // nN*256 bf16 (AGG compact / Z)
    float* stats = (float*)(BF2 + (size_t)nN * 256);  // 2048 floats, 4 layer-regions
    float* scale = stats + 2048;                      // 256 (unused, kept for layout)
    float* shift = scale + 256;                       // 256 (unused, kept for layout)
    ushort* WT   = (ushort*)(shift + 256);            // 196608 shorts
    int* degi     = (int*)(WT + 196608);              // nN
    int* cursor   = degi + nN;                        // nN (adjacent: zeroed together)
    int* rowstart = cursor + nN;                      // nN
    int* partial  = rowstart + nN;                    // 256
    int* csr      = partial + 256;                    // nE

    ushort* Wf1T = WT;
    ushort* Wf2T = WT + 32768;
    ushort* Wc1T = WT + 65536;
    ushort* Wc2T = WT + 131072;
    ushort* AGG  = BF2;                               // compact nN*128 agg buffer

    dim3 blk(256);
    auto cdiv = [](int a, int b) { return (a + b - 1) / b; };
    int nScanBlocks = cdiv(nN, 256);                  // 196 (must be <= 256)

    // ---- fused setup: weight transpose + zero stats/degi/cursor (node convert in FF1) ----
    int nZero4 = (2 * nN) / 4;
    int nbZero = cdiv(nZero4, 256);
    setup_all<<<dim3(768 + nbZero + 2), blk, 0, stream>>>(
        Wf1, Wf2, Ws1, Wn1, Wn2, Ws2, WT,
        degi, nZero4, nbZero, stats);

    // ---- CSR build ----
    degcount_kernel<<<dim3(cdiv(nE, 256)), blk, 0, stream>>>(dst, degi, nE);
    scan_block_sums<<<dim3(nScanBlocks), blk, 0, stream>>>(degi, partial, nN);
    scan_final<<<dim3(nScanBlocks), blk, 0, stream>>>(degi, partial, rowstart, nN, nScanBlocks);
    fillcsr_kernel<<<dim3(cdiv(nE, 256)), blk, 0, stream>>>(src, dst, rowstart, cursor, csr, nE);

    // ---- FF1: PRE = f2bf(nodes) @ Wf1T (BNIN=3 CVT staging; K=128, N=256, stats->L0) ----
    gemm_lds<4, 4, 0, 1, 3><<<dim3(512), blk, 0, stream>>>(
        (const ushort*)nodes, Wf1T, PRE, mStrips, 256, stats, stats + 256,
        nullptr, nullptr, nullptr, nullptr, 0.f, 0.f, nullptr);

    // ---- FF2: BF1 = act(BN_L0(PRE)) @ Wf2T (BNIN=1; K=256, N=128 compact, stats->L1) ----
    gemm_lds<8, 2, 0, 1, 1><<<dim3(512), blk, 0, stream>>>(
        PRE, Wf2T, BF1, mStrips, 128, stats + 512, stats + 768,
        stats, stats + 256, gf1, bef1, invM, 0.0f, nullptr);

    // ---- gather1 (BN fused): AGG = mean-gather(ReLU(BN_L1(BF1))) ----
    gather16_bn<<<dim3(cdiv(nN * 64, 256)), blk, 0, stream>>>(
        BF1, rowstart, degi, csr, AGG, nN,
        stats + 512, stats + 768, gf2, bef2, invM);

    // ---- SAGE1: PRE = [ReLU(BN_L1(BF1)) | AGG] @ [Ws1;Wn1] (BNIN=2 dual-source;
    //      K=256, N=256, stats->L2) ----
    gemm_lds<8, 4, 0, 1, 2><<<dim3(512), blk, 0, stream>>>(
        BF1, Wc1T, PRE, mStrips, 256, stats + 1024, stats + 1280,
        stats + 512, stats + 768, gf2, bef2, invM, 0.0f, AGG);

    // ---- SAGE2: BF2 = act(BN_L2(PRE)) @ [Wn2|Ws2] (BNIN=1; K=256, N=256, NT=4 single
    //      col-group: stages A ONCE instead of twice - R13 change) ----
    gemm_lds<8, 4, 0, 0, 1><<<dim3(512), blk, 0, stream>>>(
        PRE, Wc2T, BF2, mStrips, 256, nullptr, nullptr,
        stats + 1024, stats + 1280, gs1, bs1, invM, 0.01f, nullptr);

    // ---- gather_fuse -> out(fp32) ----
    gather16_fuse<<<dim3(cdiv(nN * 64, 256)), blk, 0, stream>>>(BF2, rowstart, degi, csr, out, nN);

    // ---- final: colstats (240 blocks: was 120, only 120/256 CUs active) -> BN+LReLU ----
    colstats128<<<dim3(240), blk, 0, stream>>>(out, stats + 1536, stats + 1792, nN);
    bnact_f32<<<dim3(2048), blk, 0, stream>>>(out, stats + 1536, stats + 1792, gs2, bs2, invM,
                                              nN, 0.01f);
}

// Round 14
// 339.779 us; speedup vs baseline: 1.0485x; 1.0098x over previous
//
#include <hip/hip_runtime.h>

#define DIN 128
#define BN_EPS 1e-5f

typedef __attribute__((ext_vector_type(8))) short bf16x8;
typedef __attribute__((ext_vector_type(8))) unsigned short us8;
typedef __attribute__((ext_vector_type(4))) float f32x4;

__device__ __forceinline__ ushort f2bf(float f) {
    unsigned u = __float_as_uint(f);
    u += 0x7fffu + ((u >> 16) & 1u);
    return (ushort)(u >> 16);
}
__device__ __forceinline__ float bf2f(ushort h) {
    return __uint_as_float(((unsigned)h) << 16);
}
__device__ __forceinline__ f32x4 asf4(us8 v) {
    union { us8 u; f32x4 f; } x; x.u = v; return x.f;
}

// ======== LDS-shared streaming GEMM (R13-best config) + EXTRA piggyback work ========
// Block-shared A strip, double-buffered LDS, depth-2 prefetch, 1 barrier/strip,
// 512 GEMM blocks. Staging transform modes:
//   BNIN=0: plain bf16 copy
//   BNIN=1: BN+act of previous layer applied during staging (reads raw PRE)
//   BNIN=2: dual-source [h|agg] with BN+ReLU on h-half, identity on agg-half
//   BNIN=3: CVT - stage directly from fp32 source, f2bf convert in staging
// EXTRA (R14): CSR-scan work piggybacked on appended blocks (blockIdx >= gemmBlocks):
//   EXTRA=1: scan_block_sums(degi -> partial)     [inside FF1; needs degcount: prev dispatch]
//   EXTRA=2: scan_final(degi,partial -> rowstart) [inside FF2; needs partial: prev dispatch]
template<int KC, int NT, int LOGNG, int STATS, int BNIN, int EXTRA>
__global__ __launch_bounds__(256) void gemm_lds(
    const ushort* __restrict__ A, const ushort* __restrict__ BT,
    ushort* __restrict__ C, int mStrips, int N, int gemmBlocks,
    float* __restrict__ gsums, float* __restrict__ gsqs,
    const float* __restrict__ isums, const float* __restrict__ isqs,
    const float* __restrict__ igam, const float* __restrict__ ibet,
    float invM, float negSlope,
    const ushort* __restrict__ A2,
    const int* __restrict__ sc_degi, int* __restrict__ sc_partial,
    int* __restrict__ sc_rowstart, int sc_n, int sc_nb)
{
    int tid = threadIdx.x;

    if (EXTRA != 0 && (int)blockIdx.x >= gemmBlocks) {
        __shared__ int xs[256];
        __shared__ int xps[256];
        int b = blockIdx.x - gemmBlocks;
        if (EXTRA == 1) {
            // scan_block_sums: per-block sum of degi
            int i = b * 256 + tid;
            xs[tid] = (i < sc_n) ? sc_degi[i] : 0;
            __syncthreads();
            for (int off = 128; off > 0; off >>= 1) {
                if (tid < off) xs[tid] += xs[tid + off];
                __syncthreads();
            }
            if (tid == 0) sc_partial[b] = xs[0];
        } else {
            // scan_final: block offset from partial sums + intra-block inclusive scan
            xps[tid] = (tid < sc_nb && tid < b) ? sc_partial[tid] : 0;
            __syncthreads();
            for (int off = 128; off > 0; off >>= 1) {
                if (tid < off) xps[tid] += xps[tid + off];
                __syncthreads();
            }
            int offset = xps[0];
            int i = b * 256 + tid;
            int v = (i < sc_n) ? sc_degi[i] : 0;
            xs[tid] = v;
            __syncthreads();
            for (int off = 1; off < 256; off <<= 1) {
                int t = (tid >= off) ? xs[tid - off] : 0;
                __syncthreads();
                xs[tid] += t;
                __syncthreads();
            }
            if (i < sc_n) sc_rowstart[i] = offset + xs[tid] - v;
        }
        return;
    }

    constexpr int K = KC * 32;           // K in shorts
    constexpr int CPR = KC * 4;          // 16B chunks per row
    constexpr int LOGCPR = (KC == 4) ? 4 : 5;
    constexpr int LPL = KC / 4;          // staging chunks per lane (1 or 2)
    constexpr int LPL2 = (BNIN == 3) ? 2 * LPL : LPL;   // regs (CVT: 2 us8 per chunk)
    __shared__ ushort abuf[2][16 * K];   // double-buffered strip (2x 4/8 KB)

    int lane = tid & 63;
    int w = tid >> 6;
    int cl = lane & 15, q = lane >> 4;
    int grp = blockIdx.x & ((1 << LOGNG) - 1);
    int s0 = blockIdx.x >> LOGNG;
    int TT = gemmBlocks >> LOGNG;        // strip stride (from gemmBlocks, not gridDim)
    int colBase = grp * (4 * 16 * NT) + w * (16 * NT);
    int chBase = w * (16 * KC);          // this wave's staging chunk range

    // B fragments: loaded once (weights L2-resident)
    bf16x8 bf[NT][KC];
    #pragma unroll
    for (int nt = 0; nt < NT; nt++) {
        const ushort* bp = BT + (long)(colBase + nt * 16 + cl) * K + q * 8;
        #pragma unroll
        for (int kc = 0; kc < KC; kc++)
            bf[nt][kc] = *(const bf16x8*)(bp + kc * 32);
    }

    // BN-in-staging params: the lane's staging chunks share one K-column
    float sc8[8], sh8[8];
    const ushort* dsrc = A;              // BNIN==2: per-lane source base
    int dcol = 0;
    if (BNIN == 1) {
        int cb = ((chBase + lane) & (CPR - 1)) * 8;
        #pragma unroll
        for (int e = 0; e < 8; e++) {
            float mean = isums[cb + e] * invM;
            float var = isqs[cb + e] * invM - mean * mean;
            float s = igam[cb + e] * rsqrtf(var + BN_EPS);
            sc8[e] = s;
            sh8[e] = ibet[cb + e] - mean * s;
        }
    } else if (BNIN == 2) {
        int c = (chBase + lane) & (CPR - 1);
        dsrc = (c < 16) ? A : A2;
        dcol = (c & 15) * 8;
        if (c < 16) {
            int cb = c * 8;
            #pragma unroll
            for (int e = 0; e < 8; e++) {
                float mean = isums[cb + e] * invM;
                float var = isqs[cb + e] * invM - mean * mean;
                float s = igam[cb + e] * rsqrtf(var + BN_EPS);
                sc8[e] = s;
                sh8[e] = ibet[cb + e] - mean * s;
            }
        } else {
            #pragma unroll
            for (int e = 0; e < 8; e++) { sc8[e] = 1.0f; sh8[e] = 0.0f; }
        }
    }

    float ssum[NT], ssq[NT];
    #pragma unroll
    for (int nt = 0; nt < NT; nt++) { ssum[nt] = 0.f; ssq[nt] = 0.f; }

    auto stage_load = [&](us8 (&stg)[LPL2], int strip) {
        if (BNIN == 3) {
            const float* Af = (const float*)A;
            #pragma unroll
            for (int u = 0; u < LPL; u++) {
                int ch = chBase + u * 64 + lane;
                int r = ch >> LOGCPR;
                int c = ch & (CPR - 1);
                const float* p = Af + (long)(strip * 16 + r) * K + c * 8;
                stg[2 * u]     = *(const us8*)p;
                stg[2 * u + 1] = *(const us8*)(p + 4);
            }
        } else if (BNIN == 2) {
            #pragma unroll
            for (int u = 0; u < LPL; u++) {
                int r = (chBase + u * 64 + lane) >> LOGCPR;
                stg[u] = *(const us8*)(dsrc + ((long)(strip * 16 + r)) * 128 + dcol);
            }
        } else {
            const ushort* As = A + (long)strip * 16 * K;
            #pragma unroll
            for (int u = 0; u < LPL; u++)
                stg[u] = *(const us8*)(As + (chBase + u * 64 + lane) * 8);
        }
    };
    auto stage_write = [&](int buf, us8 (&stg)[LPL2]) {
        #pragma unroll
        for (int u = 0; u < LPL; u++) {
            int ch = chBase + u * 64 + lane;
            int r = ch >> LOGCPR;
            int c = ch & (CPR - 1);
            us8 v;
            if (BNIN == 3) {
                f32x4 lo = asf4(stg[2 * u]);
                f32x4 hi = asf4(stg[2 * u + 1]);
                us8 o;
                o[0] = f2bf(lo[0]); o[1] = f2bf(lo[1]); o[2] = f2bf(lo[2]); o[3] = f2bf(lo[3]);
                o[4] = f2bf(hi[0]); o[5] = f2bf(hi[1]); o[6] = f2bf(hi[2]); o[7] = f2bf(hi[3]);
                v = o;
            } else {
                v = stg[u];
                if (BNIN == 1 || BNIN == 2) {
                    us8 o;
                    #pragma unroll
                    for (int e = 0; e < 8; e++) {
                        float f = bf2f(v[e]) * sc8[e] + sh8[e];
                        f = (f > 0.f) ? f : f * negSlope;
                        o[e] = f2bf(f);
                    }
                    v = o;
                }
            }
            *(us8*)(abuf[buf] + (((r << LOGCPR) + (c ^ (r & 7))) * 8)) = v;
        }
    };

    us8 stgA[LPL2], stgB[LPL2];
    int s = s0;
    // prologue: abuf[0] <- s0; stgB <- s0+TT; stgA <- s0+2TT (in flight)
    stage_load(stgA, s);
    if (s + TT < mStrips) stage_load(stgB, s + TT);
    stage_write(0, stgA);
    if (s + 2 * TT < mStrips) stage_load(stgA, s + 2 * TT);
    __syncthreads();
    int cur = 0;

#define GEMM_STEP(STG)                                                                  \
    {                                                                                   \
        bf16x8 af[KC];                                                                  \
        _Pragma("unroll")                                                               \
        for (int kc = 0; kc < KC; kc++)                                                 \
            af[kc] = *(const bf16x8*)(abuf[cur] +                                       \
                     (((cl << LOGCPR) + ((kc * 4 + q) ^ (cl & 7))) * 8));               \
        if (s + TT < mStrips) stage_write(cur ^ 1, STG);                                \
        if (s + 3 * TT < mStrips) stage_load(STG, s + 3 * TT);                          \
        f32x4 acc[NT] = {};                                                             \
        _Pragma("unroll")                                                               \
        for (int kc = 0; kc < KC; kc++)                                                 \
            _Pragma("unroll")                                                           \
            for (int nt = 0; nt < NT; nt++)                                             \
                acc[nt] = __builtin_amdgcn_mfma_f32_16x16x32_bf16(af[kc], bf[nt][kc],   \
                                                                  acc[nt], 0, 0, 0);    \
        int rowBase = s * 16;                                                           \
        _Pragma("unroll")                                                               \
        for (int nt = 0; nt < NT; nt++) {                                               \
            _Pragma("unroll")                                                           \
            for (int r = 0; r < 4; r++) {                                               \
                float v = acc[nt][r];                                                   \
                long row = rowBase + q * 4 + r;                                         \
                C[row * N + colBase + nt * 16 + cl] = f2bf(v);                          \
                if (STATS) { ssum[nt] += v; ssq[nt] += v * v; }                         \
            }                                                                           \
        }                                                                               \
        __syncthreads();                                                                \
        s += TT; cur ^= 1;                                                              \
    }

    while (true) {
        GEMM_STEP(stgB);
        if (s >= mStrips) break;
        GEMM_STEP(stgA);
        if (s >= mStrips) break;
    }
#undef GEMM_STEP

    if (STATS) {
        #pragma unroll
        for (int nt = 0; nt < NT; nt++) {
            ssum[nt] += __shfl_xor(ssum[nt], 16, 64);
            ssum[nt] += __shfl_xor(ssum[nt], 32, 64);
            ssq[nt]  += __shfl_xor(ssq[nt], 16, 64);
            ssq[nt]  += __shfl_xor(ssq[nt], 32, 64);
        }
        if (q == 0) {
            #pragma unroll
            for (int nt = 0; nt < NT; nt++) {
                atomicAdd(&gsums[colBase + nt * 16 + cl], ssum[nt]);
                atomicAdd(&gsqs[colBase + nt * 16 + cl], ssq[nt]);
            }
        }
    }
}

// ======== fused setup: transpose weights, zero stats, degcount (degi pre-zeroed by memset) ========
__global__ __launch_bounds__(256) void setup_all(
    const float* __restrict__ W0, const float* __restrict__ W1,
    const float* __restrict__ W2, const float* __restrict__ W3,
    const float* __restrict__ W4, const float* __restrict__ W5,
    ushort* __restrict__ WT,
    float* __restrict__ stats,
    const int* __restrict__ dst, int* __restrict__ degi, int E)
{
    int b = blockIdx.x;
    int tid = threadIdx.x;
    if (b < 768) {
        int seg = b >> 7;
        const float* W; int logK, dstBase, stride, kOff;
        switch (seg) {
            case 0: W = W0; logK = 7; dstBase = 0;      stride = 128; kOff = 0;   break;
            case 1: W = W1; logK = 8; dstBase = 32768;  stride = 256; kOff = 0;   break;
            case 2: W = W2; logK = 7; dstBase = 65536;  stride = 256; kOff = 0;   break;
            case 3: W = W3; logK = 7; dstBase = 65536;  stride = 256; kOff = 128; break;
            case 4: W = W4; logK = 8; dstBase = 131072; stride = 256; kOff = 0;   break;
            default:W = W5; logK = 8; dstBase = 163840; stride = 256; kOff = 0;   break;
        }
        int t = (b & 127) * 256 + tid;
        int N = 32768 >> logK;
        int k = t & ((1 << logK) - 1);
        int n = t >> logK;
        WT[(long)dstBase + (long)n * stride + kOff + k] = f2bf(W[(long)k * N + n]);
        return;
    }
    b -= 768;
    if (b < 2) {
        int t = b * 256 + tid;
        if (t < 512) *(float4*)&stats[(long)t * 4] = make_float4(0, 0, 0, 0);
        return;
    }
    b -= 2;
    int i = b * 256 + tid;
    if (i < E) atomicAdd(&degi[dst[i]], 1);
}

// ======== BN params folded, fp32 in-place (final output, 128 ch) ========
__global__ __launch_bounds__(256) void bnact_f32(
    float* __restrict__ X,
    const float* __restrict__ sums, const float* __restrict__ sqs,
    const float* __restrict__ gamma, const float* __restrict__ beta, float invM,
    int nRows, float negSlope)
{
    __shared__ float ssc[128], ssh[128];
    int tid = threadIdx.x;
    if (tid < 128) {
        float mean = sums[tid] * invM;
        float var = sqs[tid] * invM - mean * mean;
        float sc = gamma[tid] * rsqrtf(var + BN_EPS);
        ssc[tid] = sc;
        ssh[tid] = beta[tid] - mean * sc;
    }
    __syncthreads();
    int cb = (tid * 4) & 127;
    float4 sc = *(const float4*)&ssc[cb];
    float4 sh = *(const float4*)&ssh[cb];
    int r0 = blockIdx.x * 8 + ((tid * 4) >> 7);
    int rstride = gridDim.x * 8;
    for (int row = r0; row < nRows; row += rstride) {
        float4 v = *(const float4*)&X[(long)row * 128 + cb];
        float a = v.x * sc.x + sh.x; a = (a > 0.f) ? a : a * negSlope;
        float b = v.y * sc.y + sh.y; b = (b > 0.f) ? b : b * negSlope;
        float d = v.z * sc.z + sh.z; d = (d > 0.f) ? d : d * negSlope;
        float e = v.w * sc.w + sh.w; e = (e > 0.f) ? e : e * negSlope;
        *(float4*)&X[(long)row * 128 + cb] = make_float4(a, b, d, e);
    }
}

// ======== column stats for final output (128 cols, register accum) ========
__global__ __launch_bounds__(256) void colstats128(
    const float* __restrict__ X, float* __restrict__ sums, float* __restrict__ sqs, int M)
{
    __shared__ float ss[128], sq[128];
    int tid = threadIdx.x;
    if (tid < 128) { ss[tid] = 0.f; sq[tid] = 0.f; }
    __syncthreads();
    int cg = tid & 31;
    int worker = (blockIdx.x << 3) | (tid >> 5);
    int totalW = gridDim.x << 3;
    float4 s4 = make_float4(0, 0, 0, 0), q4 = make_float4(0, 0, 0, 0);
    for (int r = worker; r < M; r += totalW) {
        float4 v = *(const float4*)&X[(long)r * 128 + cg * 4];
        s4.x += v.x; s4.y += v.y; s4.z += v.z; s4.w += v.w;
        q4.x += v.x * v.x; q4.y += v.y * v.y; q4.z += v.z * v.z; q4.w += v.w * v.w;
    }
    atomicAdd(&ss[cg * 4 + 0], s4.x); atomicAdd(&sq[cg * 4 + 0], q4.x);
    atomicAdd(&ss[cg * 4 + 1], s4.y); atomicAdd(&sq[cg * 4 + 1], q4.y);
    atomicAdd(&ss[cg * 4 + 2], s4.z); atomicAdd(&sq[cg * 4 + 2], q4.z);
    atomicAdd(&ss[cg * 4 + 3], s4.w); atomicAdd(&sq[cg * 4 + 3], q4.w);
    __syncthreads();
    if (tid < 128) { atomicAdd(&sums[tid], ss[tid]); atomicAdd(&sqs[tid], sq[tid]); }
}

__global__ void fillcsr_kernel(const int* __restrict__ src, const int* __restrict__ dst,
                               const int* __restrict__ rowstart, int* __restrict__ cursor,
                               int* __restrict__ csr, int E)
{
    int i = blockIdx.x * blockDim.x + threadIdx.x;
    if (i < E) {
        int d = dst[i];
        int p = atomicAdd(&cursor[d], 1);
        csr[rowstart[d] + p] = src[i];
    }
}

// ======== gather16_bn: 16-lane group per edge, BN_L1+ReLU applied inline on raw input ========
__global__ __launch_bounds__(256) void gather16_bn(
    const ushort* __restrict__ X, const int* __restrict__ rowstart,
    const int* __restrict__ degi, const int* __restrict__ csr,
    ushort* __restrict__ AGG, int nN,
    const float* __restrict__ isums, const float* __restrict__ isqs,
    const float* __restrict__ igam, const float* __restrict__ ibet, float invM)
{
    int wv = (blockIdx.x * blockDim.x + threadIdx.x) >> 6;
    int lane = threadIdx.x & 63;
    if (wv >= nN) return;
    int g = lane >> 4;        // edge slot 0..3
    int sc = lane & 15;       // 16-B chunk of row
    float sc8[8], sh8[8];
    {
        int cb = sc * 8;
        #pragma unroll
        for (int e = 0; e < 8; e++) {
            float mean = isums[cb + e] * invM;
            float var = isqs[cb + e] * invM - mean * mean;
            float s = igam[cb + e] * rsqrtf(var + BN_EPS);
            sc8[e] = s;
            sh8[e] = ibet[cb + e] - mean * s;
        }
    }
    int start = rowstart[wv], d = degi[wv];
    const ushort* Xc = X + sc * 8;
    float acc[8] = {};
    auto accbn8 = [&](us8 v) {
        #pragma unroll
        for (int e = 0; e < 8; e++)
            acc[e] += fmaxf(bf2f(v[e]) * sc8[e] + sh8[e], 0.f);
    };
    if (d > 0) {
        int dm = (d < 64) ? d : 64;
        int idx_l = csr[start + ((lane < dm) ? lane : (dm - 1))];
        int j = 0;
        for (; j + 8 <= dm; j += 8) {
            int i0 = __shfl(idx_l, j + g, 64);
            int i1 = __shfl(idx_l, j + 4 + g, 64);
            us8 v0 = *(const us8*)(Xc + (long)i0 * 128);
            us8 v1 = *(const us8*)(Xc + (long)i1 * 128);
            accbn8(v0);
            accbn8(v1);
        }
        if (j + 4 <= dm) {
            int i0 = __shfl(idx_l, j + g, 64);
            us8 v0 = *(const us8*)(Xc + (long)i0 * 128);
            accbn8(v0);
            j += 4;
        }
        int rem = dm - j;
        if (rem > 0) {
            int sl = j + ((g < rem) ? g : (rem - 1));
            int i0 = __shfl(idx_l, sl, 64);
            if (g < rem) {
                us8 v0 = *(const us8*)(Xc + (long)i0 * 128);
                accbn8(v0);
            }
        }
        for (int jj = 64; jj < d; jj += 4) {     // rare: degree > 64
            if (jj + g < d) {
                int i0 = csr[start + jj + g];
                us8 v0 = *(const us8*)(Xc + (long)i0 * 128);
                accbn8(v0);
            }
        }
    }
    #pragma unroll
    for (int e = 0; e < 8; e++) {
        acc[e] += __shfl_xor(acc[e], 16, 64);
        acc[e] += __shfl_xor(acc[e], 32, 64);
    }
    if (g == 0) {
        float inv = 1.f / fmaxf((float)d, 1.f);
        us8 o;
        #pragma unroll
        for (int e = 0; e < 8; e++) o[e] = f2bf(acc[e] * inv);
        *(us8*)(AGG + (long)wv * 128 + sc * 8) = o;
    }
}

// fused gather2: out = mean(Z[src, 0:128]) + Z[dst, 128:256]  (fp32 out, 128 cols)
__device__ __forceinline__ void acc8(float acc[8], us8 v) {
    #pragma unroll
    for (int e = 0; e < 8; e++) acc[e] += bf2f(v[e]);
}

__global__ __launch_bounds__(256) void gather16_fuse(
    const ushort* __restrict__ Z, const int* __restrict__ rowstart,
    const int* __restrict__ degi, const int* __restrict__ csr,
    float* __restrict__ O, int nN)
{
    int wv = (blockIdx.x * blockDim.x + threadIdx.x) >> 6;
    int lane = threadIdx.x & 63;
    if (wv >= nN) return;
    int g = lane >> 4;
    int sc = lane & 15;
    int start = rowstart[wv], d = degi[wv];
    const ushort* Zc = Z + sc * 8;
    us8 selfv = *(const us8*)(Zc + (long)wv * 256 + 128);   // independent, issued early
    float acc[8] = {};
    if (d > 0) {
        int dm = (d < 64) ? d : 64;
        int idx_l = csr[start + ((lane < dm) ? lane : (dm - 1))];
        int j = 0;
        for (; j + 8 <= dm; j += 8) {
            int i0 = __shfl(idx_l, j + g, 64);
            int i1 = __shfl(idx_l, j + 4 + g, 64);
            us8 v0 = *(const us8*)(Zc + (long)i0 * 256);
            us8 v1 = *(const us8*)(Zc + (long)i1 * 256);
            acc8(acc, v0);
            acc8(acc, v1);
        }
        if (j + 4 <= dm) {
            int i0 = __shfl(idx_l, j + g, 64);
            us8 v0 = *(const us8*)(Zc + (long)i0 * 256);
            acc8(acc, v0);
            j += 4;
        }
        int rem = dm - j;
        if (rem > 0) {
            int sl = j + ((g < rem) ? g : (rem - 1));
            int i0 = __shfl(idx_l, sl, 64);
            if (g < rem) {
                us8 v0 = *(const us8*)(Zc + (long)i0 * 256);
                acc8(acc, v0);
            }
        }
        for (int jj = 64; jj < d; jj += 4) {
            if (jj + g < d) {
                int i0 = csr[start + jj + g];
                us8 v0 = *(const us8*)(Zc + (long)i0 * 256);
                acc8(acc, v0);
            }
        }
    }
    #pragma unroll
    for (int e = 0; e < 8; e++) {
        acc[e] += __shfl_xor(acc[e], 16, 64);
        acc[e] += __shfl_xor(acc[e], 32, 64);
    }
    if (g == 0) {
        float inv = 1.f / fmaxf((float)d, 1.f);
        float r[8];
        #pragma unroll
        for (int e = 0; e < 8; e++) r[e] = acc[e] * inv + bf2f(selfv[e]);
        float* op = O + (long)wv * 128 + sc * 8;
        *(float4*)op = make_float4(r[0], r[1], r[2], r[3]);
        *(float4*)(op + 4) = make_float4(r[4], r[5], r[6], r[7]);
    }
}

extern "C" void kernel_launch(void* const* d_in, const int* in_sizes, int n_in,
                              void* d_out, int out_size, void* d_ws, size_t ws_size,
                              hipStream_t stream)
{
    const float* nodes = (const float*)d_in[0];
    const int*   src   = (const int*)d_in[1];
    const int*   dst   = (const int*)d_in[2];
    const float* Wf1   = (const float*)d_in[3];
    const float* gf1   = (const float*)d_in[5];
    const float* bef1  = (const float*)d_in[6];
    const float* Wf2   = (const float*)d_in[7];
    const float* gf2   = (const float*)d_in[9];
    const float* bef2  = (const float*)d_in[10];
    const float* Ws1   = (const float*)d_in[11];
    const float* Wn1   = (const float*)d_in[12];
    const float* gs1   = (const float*)d_in[14];
    const float* bs1   = (const float*)d_in[15];
    const float* Ws2   = (const float*)d_in[16];
    const float* Wn2   = (const float*)d_in[17];
    const float* gs2   = (const float*)d_in[19];
    const float* bs2   = (const float*)d_in[20];
    // pre-BN biases (bf1,bf2,b1,b2) cancel under BatchNorm -> skipped

    int nN = in_sizes[0] / DIN;   // 50000
    int nE = in_sizes[1];         // 600000
    float* out = (float*)d_out;
    int mStrips = nN / 16;        // 3125 (exact)
    float invM = 1.0f / nN;

    // ---- workspace (identical layout to passing version) ----
    ushort* PRE = (ushort*)d_ws;                      // nN*256 bf16 raw GEMM out
    ushort* BF1 = PRE + (size_t)nN * 256;             // nN*256 bf16 (FF2 raw, compact 128)
    ushort* BF2 = BF1 + (size_t)nN * 256;             // nN*256 bf16 (AGG compact / Z)
    float* stats = (float*)(BF2 + (size_t)nN * 256);  // 2048 floats, 4 layer-regions
    float* scale = stats + 2048;                      // 256 (unused, kept for layout)
    float* shift = scale + 256;                       // 256 (unused, kept for layout)
    ushort* WT   = (ushort*)(shift + 256);            // 196608 shorts
    int* degi     = (int*)(WT + 196608);              // nN
    int* cursor   = degi + nN;                        // nN (adjacent: one memset)
    int* rowstart = cursor + nN;                      // nN
    int* partial  = rowstart + nN;                    // 256
    int* csr      = partial + 256;                    // nE

    ushort* Wf1T = WT;
    ushort* Wf2T = WT + 32768;
    ushort* Wc1T = WT + 65536;
    ushort* Wc2T = WT + 131072;
    ushort* AGG  = BF2;                               // compact nN*128 agg buffer

    dim3 blk(256);
    auto cdiv = [](int a, int b) { return (a + b - 1) / b; };
    int nScanBlocks = cdiv(nN, 256);                  // 196 (must be <= 256)
    int nbE = cdiv(nE, 256);                          // 2344

    // ---- degi/cursor zero (must precede degcount inside setup_all) ----
    hipMemsetAsync(degi, 0, 2 * (size_t)nN * sizeof(int), stream);

    // ---- fused setup: weight transpose + stats zero + degcount ----
    setup_all<<<dim3(768 + 2 + nbE), blk, 0, stream>>>(
        Wf1, Wf2, Ws1, Wn1, Wn2, Ws2, WT, stats, dst, degi, nE);

    // ---- FF1 (+piggybacked scan_block_sums): PRE = f2bf(nodes) @ Wf1T ----
    gemm_lds<4, 4, 0, 1, 3, 1><<<dim3(512 + nScanBlocks), blk, 0, stream>>>(
        (const ushort*)nodes, Wf1T, PRE, mStrips, 256, 512, stats, stats + 256,
        nullptr, nullptr, nullptr, nullptr, 0.f, 0.f, nullptr,
        degi, partial, nullptr, nN, 0);

    // ---- FF2 (+piggybacked scan_final): BF1 = act(BN_L0(PRE)) @ Wf2T ----
    gemm_lds<8, 2, 0, 1, 1, 2><<<dim3(512 + nScanBlocks), blk, 0, stream>>>(
        PRE, Wf2T, BF1, mStrips, 128, 512, stats + 512, stats + 768,
        stats, stats + 256, gf1, bef1, invM, 0.0f, nullptr,
        degi, partial, rowstart, nN, nScanBlocks);

    // ---- fillcsr (needs rowstart) ----
    fillcsr_kernel<<<dim3(nbE), blk, 0, stream>>>(src, dst, rowstart, cursor, csr, nE);

    // ---- gather1 (BN fused): AGG = mean-gather(ReLU(BN_L1(BF1))) ----
    gather16_bn<<<dim3(cdiv(nN * 64, 256)), blk, 0, stream>>>(
        BF1, rowstart, degi, csr, AGG, nN,
        stats + 512, stats + 768, gf2, bef2, invM);

    // ---- SAGE1: PRE = [ReLU(BN_L1(BF1)) | AGG] @ [Ws1;Wn1] (BNIN=2 dual-source) ----
    gemm_lds<8, 4, 0, 1, 2, 0><<<dim3(512), blk, 0, stream>>>(
        BF1, Wc1T, PRE, mStrips, 256, 512, stats + 1024, stats + 1280,
        stats + 512, stats + 768, gf2, bef2, invM, 0.0f, AGG,
        nullptr, nullptr, nullptr, 0, 0);

    // ---- SAGE2: BF2 = act(BN_L2(PRE)) @ [Wn2|Ws2] (BNIN=1; NT=4 single col-group) ----
    gemm_lds<8, 4, 0, 0, 1, 0><<<dim3(512), blk, 0, stream>>>(
        PRE, Wc2T, BF2, mStrips, 256, 512, nullptr, nullptr,
        stats + 1024, stats + 1280, gs1, bs1, invM, 0.01f, nullptr,
        nullptr, nullptr, nullptr, 0, 0);

    // ---- gather_fuse -> out(fp32) ----
    gather16_fuse<<<dim3(cdiv(nN * 64, 256)), blk, 0, stream>>>(BF2, rowstart, degi, csr, out, nN);

    // ---- final: colstats -> fused BN+LReLU on out ----
    colstats128<<<dim3(240), blk, 0, stream>>>(out, stats + 1536, stats + 1792, nN);
    bnact_f32<<<dim3(2048), blk, 0, stream>>>(out, stats + 1536, stats + 1792, gs2, bs2, invM,
                                              nN, 0.01f);
}

// Round 15
// 336.374 us; speedup vs baseline: 1.0591x; 1.0101x over previous
//
#include <hip/hip_runtime.h>

#define DIN 128
#define BN_EPS 1e-5f

typedef __attribute__((ext_vector_type(8))) short bf16x8;
typedef __attribute__((ext_vector_type(8))) unsigned short us8;
typedef __attribute__((ext_vector_type(4))) float f32x4;

__device__ __forceinline__ ushort f2bf(float f) {
    unsigned u = __float_as_uint(f);
    u += 0x7fffu + ((u >> 16) & 1u);
    return (ushort)(u >> 16);
}
__device__ __forceinline__ float bf2f(ushort h) {
    return __uint_as_float(((unsigned)h) << 16);
}
__device__ __forceinline__ f32x4 asf4(us8 v) {
    union { us8 u; f32x4 f; } x; x.u = v; return x.f;
}

// ======== LDS-shared streaming GEMM (R14 config) + EXTRA piggyback work ========
// Block-shared A strip, double-buffered LDS, depth-2 prefetch, 1 barrier/strip,
// 512 GEMM blocks. Staging transform modes:
//   BNIN=0: plain bf16 copy
//   BNIN=1: BN+act of previous layer applied during staging (reads raw PRE)
//   BNIN=2: dual-source [h|agg] with BN+ReLU on h-half, identity on agg-half
//   BNIN=3: CVT - stage directly from fp32 source, f2bf convert in staging
// EXTRA: CSR-scan work piggybacked on appended blocks (blockIdx >= gemmBlocks):
//   EXTRA=1: scan_block_sums(degi -> partial)     [inside FF1]
//   EXTRA=2: scan_final(degi,partial -> rowstart) [inside FF2]
// SPLITC (R15): write C halves to two compact 128-col buffers (C = cols 0-127,
//   C2 = cols 128-255; per-wave uniform) -> random gather downstream touches a
//   dense 12.8MB array instead of strided halves of 25.6MB (L2 footprint halved).
template<int KC, int NT, int LOGNG, int STATS, int BNIN, int EXTRA, int SPLITC>
__global__ __launch_bounds__(256) void gemm_lds(
    const ushort* __restrict__ A, const ushort* __restrict__ BT,
    ushort* __restrict__ C, int mStrips, int N, int gemmBlocks,
    float* __restrict__ gsums, float* __restrict__ gsqs,
    const float* __restrict__ isums, const float* __restrict__ isqs,
    const float* __restrict__ igam, const float* __restrict__ ibet,
    float invM, float negSlope,
    const ushort* __restrict__ A2,
    const int* __restrict__ sc_degi, int* __restrict__ sc_partial,
    int* __restrict__ sc_rowstart, int sc_n, int sc_nb,
    ushort* __restrict__ C2)
{
    int tid = threadIdx.x;

    if (EXTRA != 0 && (int)blockIdx.x >= gemmBlocks) {
        __shared__ int xs[256];
        __shared__ int xps[256];
        int b = blockIdx.x - gemmBlocks;
        if (EXTRA == 1) {
            // scan_block_sums: per-block sum of degi
            int i = b * 256 + tid;
            xs[tid] = (i < sc_n) ? sc_degi[i] : 0;
            __syncthreads();
            for (int off = 128; off > 0; off >>= 1) {
                if (tid < off) xs[tid] += xs[tid + off];
                __syncthreads();
            }
            if (tid == 0) sc_partial[b] = xs[0];
        } else {
            // scan_final: block offset from partial sums + intra-block inclusive scan
            xps[tid] = (tid < sc_nb && tid < b) ? sc_partial[tid] : 0;
            __syncthreads();
            for (int off = 128; off > 0; off >>= 1) {
                if (tid < off) xps[tid] += xps[tid + off];
                __syncthreads();
            }
            int offset = xps[0];
            int i = b * 256 + tid;
            int v = (i < sc_n) ? sc_degi[i] : 0;
            xs[tid] = v;
            __syncthreads();
            for (int off = 1; off < 256; off <<= 1) {
                int t = (tid >= off) ? xs[tid - off] : 0;
                __syncthreads();
                xs[tid] += t;
                __syncthreads();
            }
            if (i < sc_n) sc_rowstart[i] = offset + xs[tid] - v;
        }
        return;
    }

    constexpr int K = KC * 32;           // K in shorts
    constexpr int CPR = KC * 4;          // 16B chunks per row
    constexpr int LOGCPR = (KC == 4) ? 4 : 5;
    constexpr int LPL = KC / 4;          // staging chunks per lane (1 or 2)
    constexpr int LPL2 = (BNIN == 3) ? 2 * LPL : LPL;   // regs (CVT: 2 us8 per chunk)
    __shared__ ushort abuf[2][16 * K];   // double-buffered strip (2x 4/8 KB)

    int lane = tid & 63;
    int w = tid >> 6;
    int cl = lane & 15, q = lane >> 4;
    int grp = blockIdx.x & ((1 << LOGNG) - 1);
    int s0 = blockIdx.x >> LOGNG;
    int TT = gemmBlocks >> LOGNG;        // strip stride (from gemmBlocks, not gridDim)
    int colBase = grp * (4 * 16 * NT) + w * (16 * NT);
    int chBase = w * (16 * KC);          // this wave's staging chunk range

    // SPLITC: per-wave output target (halves are per-wave uniform for NT=4, LOGNG=0)
    ushort* Cw = C;
    int colW = colBase;
    int Nw = N;
    if (SPLITC) {
        Cw = (colBase < 128) ? C : C2;
        colW = colBase & 127;
        Nw = 128;
    }

    // B fragments: loaded once (weights L2-resident)
    bf16x8 bf[NT][KC];
    #pragma unroll
    for (int nt = 0; nt < NT; nt++) {
        const ushort* bp = BT + (long)(colBase + nt * 16 + cl) * K + q * 8;
        #pragma unroll
        for (int kc = 0; kc < KC; kc++)
            bf[nt][kc] = *(const bf16x8*)(bp + kc * 32);
    }

    // BN-in-staging params: the lane's staging chunks share one K-column
    float sc8[8], sh8[8];
    const ushort* dsrc = A;              // BNIN==2: per-lane source base
    int dcol = 0;
    if (BNIN == 1) {
        int cb = ((chBase + lane) & (CPR - 1)) * 8;
        #pragma unroll
        for (int e = 0; e < 8; e++) {
            float mean = isums[cb + e] * invM;
            float var = isqs[cb + e] * invM - mean * mean;
            float s = igam[cb + e] * rsqrtf(var + BN_EPS);
            sc8[e] = s;
            sh8[e] = ibet[cb + e] - mean * s;
        }
    } else if (BNIN == 2) {
        int c = (chBase + lane) & (CPR - 1);
        dsrc = (c < 16) ? A : A2;
        dcol = (c & 15) * 8;
        if (c < 16) {
            int cb = c * 8;
            #pragma unroll
            for (int e = 0; e < 8; e++) {
                float mean = isums[cb + e] * invM;
                float var = isqs[cb + e] * invM - mean * mean;
                float s = igam[cb + e] * rsqrtf(var + BN_EPS);
                sc8[e] = s;
                sh8[e] = ibet[cb + e] - mean * s;
            }
        } else {
            #pragma unroll
            for (int e = 0; e < 8; e++) { sc8[e] = 1.0f; sh8[e] = 0.0f; }
        }
    }

    float ssum[NT], ssq[NT];
    #pragma unroll
    for (int nt = 0; nt < NT; nt++) { ssum[nt] = 0.f; ssq[nt] = 0.f; }

    auto stage_load = [&](us8 (&stg)[LPL2], int strip) {
        if (BNIN == 3) {
            const float* Af = (const float*)A;
            #pragma unroll
            for (int u = 0; u < LPL; u++) {
                int ch = chBase + u * 64 + lane;
                int r = ch >> LOGCPR;
                int c = ch & (CPR - 1);
                const float* p = Af + (long)(strip * 16 + r) * K + c * 8;
                stg[2 * u]     = *(const us8*)p;
                stg[2 * u + 1] = *(const us8*)(p + 4);
            }
        } else if (BNIN == 2) {
            #pragma unroll
            for (int u = 0; u < LPL; u++) {
                int r = (chBase + u * 64 + lane) >> LOGCPR;
                stg[u] = *(const us8*)(dsrc + ((long)(strip * 16 + r)) * 128 + dcol);
            }
        } else {
            const ushort* As = A + (long)strip * 16 * K;
            #pragma unroll
            for (int u = 0; u < LPL; u++)
                stg[u] = *(const us8*)(As + (chBase + u * 64 + lane) * 8);
        }
    };
    auto stage_write = [&](int buf, us8 (&stg)[LPL2]) {
        #pragma unroll
        for (int u = 0; u < LPL; u++) {
            int ch = chBase + u * 64 + lane;
            int r = ch >> LOGCPR;
            int c = ch & (CPR - 1);
            us8 v;
            if (BNIN == 3) {
                f32x4 lo = asf4(stg[2 * u]);
                f32x4 hi = asf4(stg[2 * u + 1]);
                us8 o;
                o[0] = f2bf(lo[0]); o[1] = f2bf(lo[1]); o[2] = f2bf(lo[2]); o[3] = f2bf(lo[3]);
                o[4] = f2bf(hi[0]); o[5] = f2bf(hi[1]); o[6] = f2bf(hi[2]); o[7] = f2bf(hi[3]);
                v = o;
            } else {
                v = stg[u];
                if (BNIN == 1 || BNIN == 2) {
                    us8 o;
                    #pragma unroll
                    for (int e = 0; e < 8; e++) {
                        float f = bf2f(v[e]) * sc8[e] + sh8[e];
                        f = (f > 0.f) ? f : f * negSlope;
                        o[e] = f2bf(f);
                    }
                    v = o;
                }
            }
            *(us8*)(abuf[buf] + (((r << LOGCPR) + (c ^ (r & 7))) * 8)) = v;
        }
    };

    us8 stgA[LPL2], stgB[LPL2];
    int s = s0;
    // prologue: abuf[0] <- s0; stgB <- s0+TT; stgA <- s0+2TT (in flight)
    stage_load(stgA, s);
    if (s + TT < mStrips) stage_load(stgB, s + TT);
    stage_write(0, stgA);
    if (s + 2 * TT < mStrips) stage_load(stgA, s + 2 * TT);
    __syncthreads();
    int cur = 0;

#define GEMM_STEP(STG)                                                                  \
    {                                                                                   \
        bf16x8 af[KC];                                                                  \
        _Pragma("unroll")                                                               \
        for (int kc = 0; kc < KC; kc++)                                                 \
            af[kc] = *(const bf16x8*)(abuf[cur] +                                       \
                     (((cl << LOGCPR) + ((kc * 4 + q) ^ (cl & 7))) * 8));               \
        if (s + TT < mStrips) stage_write(cur ^ 1, STG);                                \
        if (s + 3 * TT < mStrips) stage_load(STG, s + 3 * TT);                          \
        f32x4 acc[NT] = {};                                                             \
        _Pragma("unroll")                                                               \
        for (int kc = 0; kc < KC; kc++)                                                 \
            _Pragma("unroll")                                                           \
            for (int nt = 0; nt < NT; nt++)                                             \
                acc[nt] = __builtin_amdgcn_mfma_f32_16x16x32_bf16(af[kc], bf[nt][kc],   \
                                                                  acc[nt], 0, 0, 0);    \
        int rowBase = s * 16;                                                           \
        _Pragma("unroll")                                                               \
        for (int nt = 0; nt < NT; nt++) {                                               \
            _Pragma("unroll")                                                           \
            for (int r = 0; r < 4; r++) {                                               \
                float v = acc[nt][r];                                                   \
                long row = rowBase + q * 4 + r;                                         \
                Cw[row * Nw + colW + nt * 16 + cl] = f2bf(v);                           \
                if (STATS) { ssum[nt] += v; ssq[nt] += v * v; }                         \
            }                                                                           \
        }                                                                               \
        __syncthreads();                                                                \
        s += TT; cur ^= 1;                                                              \
    }

    while (true) {
        GEMM_STEP(stgB);
        if (s >= mStrips) break;
        GEMM_STEP(stgA);
        if (s >= mStrips) break;
    }
#undef GEMM_STEP

    if (STATS) {
        #pragma unroll
        for (int nt = 0; nt < NT; nt++) {
            ssum[nt] += __shfl_xor(ssum[nt], 16, 64);
            ssum[nt] += __shfl_xor(ssum[nt], 32, 64);
            ssq[nt]  += __shfl_xor(ssq[nt], 16, 64);
            ssq[nt]  += __shfl_xor(ssq[nt], 32, 64);
        }
        if (q == 0) {
            #pragma unroll
            for (int nt = 0; nt < NT; nt++) {
                atomicAdd(&gsums[colBase + nt * 16 + cl], ssum[nt]);
                atomicAdd(&gsqs[colBase + nt * 16 + cl], ssq[nt]);
            }
        }
    }
}

// ======== fused setup: weight transpose, stats zero, cursor zero, degcount ========
// (degi pre-zeroed by memset; cursor zeroed here - not needed until fillcsr, 3 dispatches later)
__global__ __launch_bounds__(256) void setup_all(
    const float* __restrict__ W0, const float* __restrict__ W1,
    const float* __restrict__ W2, const float* __restrict__ W3,
    const float* __restrict__ W4, const float* __restrict__ W5,
    ushort* __restrict__ WT,
    float* __restrict__ stats,
    int* __restrict__ cursor, int nCur4, int nbCur,
    const int* __restrict__ dst, int* __restrict__ degi, int E)
{
    int b = blockIdx.x;
    int tid = threadIdx.x;
    if (b < 768) {
        int seg = b >> 7;
        const float* W; int logK, dstBase, stride, kOff;
        switch (seg) {
            case 0: W = W0; logK = 7; dstBase = 0;      stride = 128; kOff = 0;   break;
            case 1: W = W1; logK = 8; dstBase = 32768;  stride = 256; kOff = 0;   break;
            case 2: W = W2; logK = 7; dstBase = 65536;  stride = 256; kOff = 0;   break;
            case 3: W = W3; logK = 7; dstBase = 65536;  stride = 256; kOff = 128; break;
            case 4: W = W4; logK = 8; dstBase = 131072; stride = 256; kOff = 0;   break;
            default:W = W5; logK = 8; dstBase = 163840; stride = 256; kOff = 0;   break;
        }
        int t = (b & 127) * 256 + tid;
        int N = 32768 >> logK;
        int k = t & ((1 << logK) - 1);
        int n = t >> logK;
        WT[(long)dstBase + (long)n * stride + kOff + k] = f2bf(W[(long)k * N + n]);
        return;
    }
    b -= 768;
    if (b < 2) {
        int t = b * 256 + tid;
        if (t < 512) *(float4*)&stats[(long)t * 4] = make_float4(0, 0, 0, 0);
        return;
    }
    b -= 2;
    if (b < nbCur) {
        int t = b * 256 + tid;
        if (t < nCur4) *(int4*)&cursor[(long)t * 4] = make_int4(0, 0, 0, 0);
        return;
    }
    b -= nbCur;
    int i = b * 256 + tid;
    if (i < E) atomicAdd(&degi[dst[i]], 1);
}

// ======== BN params folded, fp32 in-place (final output, 128 ch) ========
__global__ __launch_bounds__(256) void bnact_f32(
    float* __restrict__ X,
    const float* __restrict__ sums, const float* __restrict__ sqs,
    const float* __restrict__ gamma, const float* __restrict__ beta, float invM,
    int nRows, float negSlope)
{
    __shared__ float ssc[128], ssh[128];
    int tid = threadIdx.x;
    if (tid < 128) {
        float mean = sums[tid] * invM;
        float var = sqs[tid] * invM - mean * mean;
        float sc = gamma[tid] * rsqrtf(var + BN_EPS);
        ssc[tid] = sc;
        ssh[tid] = beta[tid] - mean * sc;
    }
    __syncthreads();
    int cb = (tid * 4) & 127;
    float4 sc = *(const float4*)&ssc[cb];
    float4 sh = *(const float4*)&ssh[cb];
    int r0 = blockIdx.x * 8 + ((tid * 4) >> 7);
    int rstride = gridDim.x * 8;
    for (int row = r0; row < nRows; row += rstride) {
        float4 v = *(const float4*)&X[(long)row * 128 + cb];
        float a = v.x * sc.x + sh.x; a = (a > 0.f) ? a : a * negSlope;
        float b = v.y * sc.y + sh.y; b = (b > 0.f) ? b : b * negSlope;
        float d = v.z * sc.z + sh.z; d = (d > 0.f) ? d : d * negSlope;
        float e = v.w * sc.w + sh.w; e = (e > 0.f) ? e : e * negSlope;
        *(float4*)&X[(long)row * 128 + cb] = make_float4(a, b, d, e);
    }
}

// ======== column stats for final output (128 cols, register accum) ========
__global__ __launch_bounds__(256) void colstats128(
    const float* __restrict__ X, float* __restrict__ sums, float* __restrict__ sqs, int M)
{
    __shared__ float ss[128], sq[128];
    int tid = threadIdx.x;
    if (tid < 128) { ss[tid] = 0.f; sq[tid] = 0.f; }
    __syncthreads();
    int cg = tid & 31;
    int worker = (blockIdx.x << 3) | (tid >> 5);
    int totalW = gridDim.x << 3;
    float4 s4 = make_float4(0, 0, 0, 0), q4 = make_float4(0, 0, 0, 0);
    for (int r = worker; r < M; r += totalW) {
        float4 v = *(const float4*)&X[(long)r * 128 + cg * 4];
        s4.x += v.x; s4.y += v.y; s4.z += v.z; s4.w += v.w;
        q4.x += v.x * v.x; q4.y += v.y * v.y; q4.z += v.z * v.z; q4.w += v.w * v.w;
    }
    atomicAdd(&ss[cg * 4 + 0], s4.x); atomicAdd(&sq[cg * 4 + 0], q4.x);
    atomicAdd(&ss[cg * 4 + 1], s4.y); atomicAdd(&sq[cg * 4 + 1], q4.y);
    atomicAdd(&ss[cg * 4 + 2], s4.z); atomicAdd(&sq[cg * 4 + 2], q4.z);
    atomicAdd(&ss[cg * 4 + 3], s4.w); atomicAdd(&sq[cg * 4 + 3], q4.w);
    __syncthreads();
    if (tid < 128) { atomicAdd(&sums[tid], ss[tid]); atomicAdd(&sqs[tid], sq[tid]); }
}

__global__ void fillcsr_kernel(const int* __restrict__ src, const int* __restrict__ dst,
                               const int* __restrict__ rowstart, int* __restrict__ cursor,
                               int* __restrict__ csr, int E)
{
    int i = blockIdx.x * blockDim.x + threadIdx.x;
    if (i < E) {
        int d = dst[i];
        int p = atomicAdd(&cursor[d], 1);
        csr[rowstart[d] + p] = src[i];
    }
}

// ======== gather16_bn: 16-lane group per edge, BN_L1+ReLU applied inline on raw input ========
__global__ __launch_bounds__(256) void gather16_bn(
    const ushort* __restrict__ X, const int* __restrict__ rowstart,
    const int* __restrict__ degi, const int* __restrict__ csr,
    ushort* __restrict__ AGG, int nN,
    const float* __restrict__ isums, const float* __restrict__ isqs,
    const float* __restrict__ igam, const float* __restrict__ ibet, float invM)
{
    int wv = (blockIdx.x * blockDim.x + threadIdx.x) >> 6;
    int lane = threadIdx.x & 63;
    if (wv >= nN) return;
    int g = lane >> 4;        // edge slot 0..3
    int sc = lane & 15;       // 16-B chunk of row
    float sc8[8], sh8[8];
    {
        int cb = sc * 8;
        #pragma unroll
        for (int e = 0; e < 8; e++) {
            float mean = isums[cb + e] * invM;
            float var = isqs[cb + e] * invM - mean * mean;
            float s = igam[cb + e] * rsqrtf(var + BN_EPS);
            sc8[e] = s;
            sh8[e] = ibet[cb + e] - mean * s;
        }
    }
    int start = rowstart[wv], d = degi[wv];
    const ushort* Xc = X + sc * 8;
    float acc[8] = {};
    auto accbn8 = [&](us8 v) {
        #pragma unroll
        for (int e = 0; e < 8; e++)
            acc[e] += fmaxf(bf2f(v[e]) * sc8[e] + sh8[e], 0.f);
    };
    if (d > 0) {
        int dm = (d < 64) ? d : 64;
        int idx_l = csr[start + ((lane < dm) ? lane : (dm - 1))];
        int j = 0;
        for (; j + 8 <= dm; j += 8) {
            int i0 = __shfl(idx_l, j + g, 64);
            int i1 = __shfl(idx_l, j + 4 + g, 64);
            us8 v0 = *(const us8*)(Xc + (long)i0 * 128);
            us8 v1 = *(const us8*)(Xc + (long)i1 * 128);
            accbn8(v0);
            accbn8(v1);
        }
        if (j + 4 <= dm) {
            int i0 = __shfl(idx_l, j + g, 64);
            us8 v0 = *(const us8*)(Xc + (long)i0 * 128);
            accbn8(v0);
            j += 4;
        }
        int rem = dm - j;
        if (rem > 0) {
            int sl = j + ((g < rem) ? g : (rem - 1));
            int i0 = __shfl(idx_l, sl, 64);
            if (g < rem) {
                us8 v0 = *(const us8*)(Xc + (long)i0 * 128);
                accbn8(v0);
            }
        }
        for (int jj = 64; jj < d; jj += 4) {     // rare: degree > 64
            if (jj + g < d) {
                int i0 = csr[start + jj + g];
                us8 v0 = *(const us8*)(Xc + (long)i0 * 128);
                accbn8(v0);
            }
        }
    }
    #pragma unroll
    for (int e = 0; e < 8; e++) {
        acc[e] += __shfl_xor(acc[e], 16, 64);
        acc[e] += __shfl_xor(acc[e], 32, 64);
    }
    if (g == 0) {
        float inv = 1.f / fmaxf((float)d, 1.f);
        us8 o;
        #pragma unroll
        for (int e = 0; e < 8; e++) o[e] = f2bf(acc[e] * inv);
        *(us8*)(AGG + (long)wv * 128 + sc * 8) = o;
    }
}

// fused gather2 (compact dual-source): out = mean(ZN[src]) + ZS[dst]  (fp32 out, 128 cols)
// ZN/ZS are compact nN*128 buffers (SAGE2 SPLITC halves) -> 12.8MB random-gather footprint.
__device__ __forceinline__ void acc8(float acc[8], us8 v) {
    #pragma unroll
    for (int e = 0; e < 8; e++) acc[e] += bf2f(v[e]);
}

__global__ __launch_bounds__(256) void gather16_fuse(
    const ushort* __restrict__ ZN, const ushort* __restrict__ ZS,
    const int* __restrict__ rowstart,
    const int* __restrict__ degi, const int* __restrict__ csr,
    float* __restrict__ O, int nN)
{
    int wv = (blockIdx.x * blockDim.x + threadIdx.x) >> 6;
    int lane = threadIdx.x & 63;
    if (wv >= nN) return;
    int g = lane >> 4;
    int sc = lane & 15;
    int start = rowstart[wv], d = degi[wv];
    const ushort* Zc = ZN + sc * 8;
    us8 selfv = *(const us8*)(ZS + (long)wv * 128 + sc * 8);   // independent, issued early
    float acc[8] = {};
    if (d > 0) {
        int dm = (d < 64) ? d : 64;
        int idx_l = csr[start + ((lane < dm) ? lane : (dm - 1))];
        int j = 0;
        for (; j + 8 <= dm; j += 8) {
            int i0 = __shfl(idx_l, j + g, 64);
            int i1 = __shfl(idx_l, j + 4 + g, 64);
            us8 v0 = *(const us8*)(Zc + (long)i0 * 128);
            us8 v1 = *(const us8*)(Zc + (long)i1 * 128);
            acc8(acc, v0);
            acc8(acc, v1);
        }
        if (j + 4 <= dm) {
            int i0 = __shfl(idx_l, j + g, 64);
            us8 v0 = *(const us8*)(Zc + (long)i0 * 128);
            acc8(acc, v0);
            j += 4;
        }
        int rem = dm - j;
        if (rem > 0) {
            int sl = j + ((g < rem) ? g : (rem - 1));
            int i0 = __shfl(idx_l, sl, 64);
            if (g < rem) {
                us8 v0 = *(const us8*)(Zc + (long)i0 * 128);
                acc8(acc, v0);
            }
        }
        for (int jj = 64; jj < d; jj += 4) {
            if (jj + g < d) {
                int i0 = csr[start + jj + g];
                us8 v0 = *(const us8*)(Zc + (long)i0 * 128);
                acc8(acc, v0);
            }
        }
    }
    #pragma unroll
    for (int e = 0; e < 8; e++) {
        acc[e] += __shfl_xor(acc[e], 16, 64);
        acc[e] += __shfl_xor(acc[e], 32, 64);
    }
    if (g == 0) {
        float inv = 1.f / fmaxf((float)d, 1.f);
        float r[8];
        #pragma unroll
        for (int e = 0; e < 8; e++) r[e] = acc[e] * inv + bf2f(selfv[e]);
        float* op = O + (long)wv * 128 + sc * 8;
        *(float4*)op = make_float4(r[0], r[1], r[2], r[3]);
        *(float4*)(op + 4) = make_float4(r[4], r[5], r[6], r[7]);
    }
}

extern "C" void kernel_launch(void* const* d_in, const int* in_sizes, int n_in,
                              void* d_out, int out_size, void* d_ws, size_t ws_size,
                              hipStream_t stream)
{
    const float* nodes = (const float*)d_in[0];
    const int*   src   = (const int*)d_in[1];
    const int*   dst   = (const int*)d_in[2];
    const float* Wf1   = (const float*)d_in[3];
    const float* gf1   = (const float*)d_in[5];
    const float* bef1  = (const float*)d_in[6];
    const float* Wf2   = (const float*)d_in[7];
    const float* gf2   = (const float*)d_in[9];
    const float* bef2  = (const float*)d_in[10];
    const float* Ws1   = (const float*)d_in[11];
    const float* Wn1   = (const float*)d_in[12];
    const float* gs1   = (const float*)d_in[14];
    const float* bs1   = (const float*)d_in[15];
    const float* Ws2   = (const float*)d_in[16];
    const float* Wn2   = (const float*)d_in[17];
    const float* gs2   = (const float*)d_in[19];
    const float* bs2   = (const float*)d_in[20];
    // pre-BN biases (bf1,bf2,b1,b2) cancel under BatchNorm -> skipped

    int nN = in_sizes[0] / DIN;   // 50000
    int nE = in_sizes[1];         // 600000
    float* out = (float*)d_out;
    int mStrips = nN / 16;        // 3125 (exact)
    float invM = 1.0f / nN;

    // ---- workspace (identical layout to passing version) ----
    ushort* PRE = (ushort*)d_ws;                      // nN*256 bf16 raw GEMM out
    ushort* BF1 = PRE + (size_t)nN * 256;             // nN*256 bf16 (FF2 raw, compact 128)
    ushort* BF2 = BF1 + (size_t)nN * 256;             // nN*256 bf16 (AGG / ZN+ZS compact)
    float* stats = (float*)(BF2 + (size_t)nN * 256);  // 2048 floats, 4 layer-regions
    float* scale = stats + 2048;                      // 256 (unused, kept for layout)
    float* shift = scale + 256;                       // 256 (unused, kept for layout)
    ushort* WT   = (ushort*)(shift + 256);            // 196608 shorts
    int* degi     = (int*)(WT + 196608);              // nN
    int* cursor   = degi + nN;                        // nN
    int* rowstart = cursor + nN;                      // nN
    int* partial  = rowstart + nN;                    // 256
    int* csr      = partial + 256;                    // nE

    ushort* Wf1T = WT;
    ushort* Wf2T = WT + 32768;
    ushort* Wc1T = WT + 65536;
    ushort* Wc2T = WT + 131072;
    ushort* AGG  = BF2;                               // compact nN*128 agg buffer (SAGE1 phase)
    ushort* ZN   = BF2;                               // compact nN*128 SAGE2 N-part (cols 0-127)
    ushort* ZS   = BF2 + (size_t)nN * 128;            // compact nN*128 SAGE2 S-part (cols 128-255)

    dim3 blk(256);
    auto cdiv = [](int a, int b) { return (a + b - 1) / b; };
    int nScanBlocks = cdiv(nN, 256);                  // 196 (must be <= 256)
    int nbE = cdiv(nE, 256);                          // 2344
    int nCur4 = nN / 4;                               // cursor int4 count (nN mult of 4)
    int nbCur = cdiv(nCur4, 256);                     // 49

    // ---- degi zero only (cursor zeroed inside setup_all; degi needed by its degcount) ----
    hipMemsetAsync(degi, 0, (size_t)nN * sizeof(int), stream);

    // ---- fused setup: weight transpose + stats zero + cursor zero + degcount ----
    setup_all<<<dim3(768 + 2 + nbCur + nbE), blk, 0, stream>>>(
        Wf1, Wf2, Ws1, Wn1, Wn2, Ws2, WT, stats,
        cursor, nCur4, nbCur, dst, degi, nE);

    // ---- FF1 (+piggybacked scan_block_sums): PRE = f2bf(nodes) @ Wf1T ----
    gemm_lds<4, 4, 0, 1, 3, 1, 0><<<dim3(512 + nScanBlocks), blk, 0, stream>>>(
        (const ushort*)nodes, Wf1T, PRE, mStrips, 256, 512, stats, stats + 256,
        nullptr, nullptr, nullptr, nullptr, 0.f, 0.f, nullptr,
        degi, partial, nullptr, nN, 0, nullptr);

    // ---- FF2 (+piggybacked scan_final): BF1 = act(BN_L0(PRE)) @ Wf2T ----
    gemm_lds<8, 2, 0, 1, 1, 2, 0><<<dim3(512 + nScanBlocks), blk, 0, stream>>>(
        PRE, Wf2T, BF1, mStrips, 128, 512, stats + 512, stats + 768,
        stats, stats + 256, gf1, bef1, invM, 0.0f, nullptr,
        degi, partial, rowstart, nN, nScanBlocks, nullptr);

    // ---- fillcsr (needs rowstart) ----
    fillcsr_kernel<<<dim3(nbE), blk, 0, stream>>>(src, dst, rowstart, cursor, csr, nE);

    // ---- gather1 (BN fused): AGG = mean-gather(ReLU(BN_L1(BF1))) ----
    gather16_bn<<<dim3(cdiv(nN * 64, 256)), blk, 0, stream>>>(
        BF1, rowstart, degi, csr, AGG, nN,
        stats + 512, stats + 768, gf2, bef2, invM);

    // ---- SAGE1: PRE = [ReLU(BN_L1(BF1)) | AGG] @ [Ws1;Wn1] (BNIN=2 dual-source) ----
    gemm_lds<8, 4, 0, 1, 2, 0, 0><<<dim3(512), blk, 0, stream>>>(
        BF1, Wc1T, PRE, mStrips, 256, 512, stats + 1024, stats + 1280,
        stats + 512, stats + 768, gf2, bef2, invM, 0.0f, AGG,
        nullptr, nullptr, nullptr, 0, 0, nullptr);

    // ---- SAGE2: {ZN|ZS} = act(BN_L2(PRE)) @ [Wn2|Ws2] (BNIN=1; SPLITC compact halves) ----
    gemm_lds<8, 4, 0, 0, 1, 0, 1><<<dim3(512), blk, 0, stream>>>(
        PRE, Wc2T, ZN, mStrips, 256, 512, nullptr, nullptr,
        stats + 1024, stats + 1280, gs1, bs1, invM, 0.01f, nullptr,
        nullptr, nullptr, nullptr, 0, 0, ZS);

    // ---- gather_fuse (compact dual-source) -> out(fp32) ----
    gather16_fuse<<<dim3(cdiv(nN * 64, 256)), blk, 0, stream>>>(
        ZN, ZS, rowstart, degi, csr, out, nN);

    // ---- final: colstats -> fused BN+LReLU on out ----
    colstats128<<<dim3(240), blk, 0, stream>>>(out, stats + 1536, stats + 1792, nN);
    bnact_f32<<<dim3(2048), blk, 0, stream>>>(out, stats + 1536, stats + 1792, gs2, bs2, invM,
                                              nN, 0.01f);
}